// Round 10
// baseline (1896.791 us; speedup 1.0000x reference)
//
#include <hip/hip_runtime.h>
#include <hip/hip_bf16.h>
#include <math.h>

#define NN 20000
#define EE 200000
#define GG 32
#define DD 384
#define HH 12
#define CC 32
#define LL 6
#define NRBF 100
#define CHUNK 32768

typedef short s16x8 __attribute__((ext_vector_type(8)));
typedef float f32x4 __attribute__((ext_vector_type(4)));
typedef unsigned int u32;

__device__ __forceinline__ float siluf(float x) { return x / (1.f + __expf(-x)); }
__device__ __forceinline__ float bf2f(unsigned short u) {
    return __uint_as_float(((unsigned int)u) << 16);
}

__device__ __forceinline__ void atomicMaxF(float* addr, float val) {
    if (val >= 0.f) atomicMax((int*)addr, __float_as_int(val));
    else atomicMin((unsigned int*)addr, __float_as_uint(val));
}

// async global->LDS, 16B per lane; LDS dest = wave-uniform base + lane*16
__device__ __forceinline__ void gload16(const void* g, void* l) {
    __builtin_amdgcn_global_load_lds((const __attribute__((address_space(1))) u32*)g,
                                     (__attribute__((address_space(3))) u32*)l, 16, 0, 0);
}

// XCD-aware tile decode: col-tiles of one row-tile run consecutively on ONE XCD
// (dispatch round-robins XCDs by linear workgroup id) -> A row-tile stays L2-hot,
// A read from HBM exactly once (verified round 7: FETCH 301->156 MB).
__device__ __forceinline__ bool tile_decode(int NC, int nrows, int& rowt, int& col) {
    const int t = blockIdx.x;
    const int q = t >> 3;
    col = q % NC;
    rowt = (q / NC) * 8 + (t & 7);
    return rowt < nrows;
}

// Symbol the harness template named; defined for safety, never launched.
__global__ void EquivariantProteinGNN_45552423141948_kernel() {}

// ---- shared BK=32 K-loop (128x128 tile, 4 waves, 16KB As + 16KB Bs).
// BK=64 tried in round 9: occupancy 31%->21%, net regression -> reverted (m132 analog).
// LDS row = 64B = 4 chunks of 16B, chunk-swizzled c ^= (row>>1)&3 via pre-swizzled
// global SOURCE + swizzled READ (same involution both sides; linear gload_lds dest).
__device__ __forceinline__ void gemm_kloop(const __hip_bfloat16* __restrict__ A,
                                           const __hip_bfloat16* __restrict__ Bt,
                                           int M, int K, int m0, int n0,
                                           unsigned short* As, unsigned short* Bs,
                                           f32x4 (&acc)[4][4]) {
    char* AsB = (char*)As;
    char* BsB = (char*)Bs;
    const int t = threadIdx.x;
    const int w = t >> 6, l = t & 63;
    const int wr = w >> 1, wc = w & 1;

    const int seg0 = 2 * w, seg1 = seg0 + 1;
    const int r0s = seg0 * 16 + (l >> 2);
    const int r1s = seg1 * 16 + (l >> 2);
    const int cg0 = (l & 3) ^ ((r0s >> 1) & 3);
    const int cg1 = (l & 3) ^ ((r1s >> 1) & 3);
    const size_t aSrc0 = (size_t)min(m0 + r0s, M - 1) * K + cg0 * 8;
    const size_t aSrc1 = (size_t)min(m0 + r1s, M - 1) * K + cg1 * 8;
    const size_t bSrc0 = (size_t)(n0 + r0s) * K + cg0 * 8;
    const size_t bSrc1 = (size_t)(n0 + r1s) * K + cg1 * 8;
    unsigned short* AsW0 = As + seg0 * 512;
    unsigned short* AsW1 = As + seg1 * 512;
    unsigned short* BsW0 = Bs + seg0 * 512;
    unsigned short* BsW1 = Bs + seg1 * 512;

    int aoff[4], boff[4];
#pragma unroll
    for (int m = 0; m < 4; ++m) {
        const int row = wr * 64 + m * 16 + (l & 15);
        aoff[m] = row * 64 + ((((l >> 4)) ^ ((row >> 1) & 3)) << 4);
        const int rowb = wc * 64 + m * 16 + (l & 15);
        boff[m] = rowb * 64 + ((((l >> 4)) ^ ((rowb >> 1) & 3)) << 4);
    }

    for (int kk = 0; kk < K; kk += 32) {
        __syncthreads();
        gload16(A + aSrc0 + kk, AsW0);
        gload16(A + aSrc1 + kk, AsW1);
        gload16(Bt + bSrc0 + kk, BsW0);
        gload16(Bt + bSrc1 + kk, BsW1);
        __syncthreads();
        s16x8 af[4], bfr[4];
#pragma unroll
        for (int m = 0; m < 4; ++m) af[m] = *(const s16x8*)(AsB + aoff[m]);
#pragma unroll
        for (int n = 0; n < 4; ++n) bfr[n] = *(const s16x8*)(BsB + boff[n]);
#pragma unroll
        for (int m = 0; m < 4; ++m)
#pragma unroll
            for (int n = 0; n < 4; ++n)
                acc[m][n] = __builtin_amdgcn_mfma_f32_16x16x32_bf16(af[m], bfr[n], acc[m][n], 0, 0, 0);
    }
}

// ============ bf16 MFMA GEMM: C[M][N] = A[M][K] @ Bt[N][K]^T (+bias)(+silu) -> bf16 ============
template<bool BIAS, bool SILU>
__global__ __launch_bounds__(256) void k_gemm_bt(const __hip_bfloat16* __restrict__ A,
                                                 const __hip_bfloat16* __restrict__ Bt,
                                                 const float* __restrict__ bias,
                                                 __hip_bfloat16* __restrict__ Cmat,
                                                 int M, int N, int K) {
    int rowt, colt;
    if (!tile_decode(N >> 7, (M + 127) >> 7, rowt, colt)) return;
    const int m0 = rowt << 7, n0 = colt << 7;

    __shared__ unsigned short As[128 * 32];
    __shared__ unsigned short Bs[128 * 32];
    const int l = threadIdx.x & 63;
    const int w = threadIdx.x >> 6;
    const int wr = w >> 1, wc = w & 1;

    f32x4 acc[4][4] = {};
    gemm_kloop(A, Bt, M, K, m0, n0, As, Bs, acc);

#pragma unroll
    for (int n = 0; n < 4; ++n) {
        const int col = n0 + wc * 64 + n * 16 + (l & 15);
        const float bv = BIAS ? bias[col] : 0.f;
#pragma unroll
        for (int m = 0; m < 4; ++m) {
            const int rbase = m0 + wr * 64 + m * 16 + ((l >> 4) << 2);
#pragma unroll
            for (int r = 0; r < 4; ++r) {
                const int row = rbase + r;
                if (row < M) {
                    float v = acc[m][n][r] + bv;
                    if (SILU) v = siluf(v);
                    Cmat[(size_t)row * N + col] = __float2bfloat16(v);
                }
            }
        }
    }
}

// ===== fused: ee = ebf @ Wet^T, then logits[p][h] over CSR-ordered edges =====
// Epilogue via per-wave LDS transpose (aliases As/Bs). Swizzle col^(row<<2):
// verified 0 bank conflicts in round-9 counters. Gathers issued BEFORE the LDS
// scatter so their latency hides under the ds_write/ds_read work.
__global__ __launch_bounds__(256) void k_gemm_attn(const __hip_bfloat16* __restrict__ A,
                                                   const __hip_bfloat16* __restrict__ Bt,
                                                   const __hip_bfloat16* __restrict__ xlr,
                                                   const int* __restrict__ src_p,
                                                   const int* __restrict__ dst_p,
                                                   const float* __restrict__ att_i,
                                                   float* __restrict__ logits,
                                                   int M, int K) {
    int rowt, colt;
    if (!tile_decode(DD >> 7, (M + 127) >> 7, rowt, colt)) return;
    const int m0 = rowt << 7, n0 = colt << 7;

    __shared__ char smem[16384];
    unsigned short* As = (unsigned short*)smem;
    unsigned short* Bs = (unsigned short*)(smem + 8192);
    const int l = threadIdx.x & 63;
    const int w = threadIdx.x >> 6;
    const int wr = w >> 1, wc = w & 1;

    f32x4 acc[4][4] = {};
    gemm_kloop(A, Bt, M, K, m0, n0, As, Bs, acc);

    __syncthreads();  // all waves done with As/Bs; reuse as per-wave epilogue scratch

    // ---- LDS-transpose epilogue ----
    float* ep = (float*)(smem + w * 4096);  // per-wave 16x64 f32
    const int row_l = l >> 2;               // 0..15: local edge row this lane reduces
    const int c0 = (l & 3) << 4;            // 16-col slice within the 64-col window
    const int gcol = n0 + wc * 64 + c0;
    const int hbase = (n0 + wc * 64) >> 5;  // first of 2 heads in this wave's window
    const int rswz = row_l << 2;

    float attv[16];
#pragma unroll
    for (int k = 0; k < 4; ++k)
        *(float4*)(attv + 4 * k) = *(const float4*)(att_i + gcol + 4 * k);

#pragma unroll
    for (int m = 0; m < 4; ++m) {
        // issue independent gathers FIRST (latency hides under the LDS transpose)
        const int growu = m0 + wr * 64 + m * 16 + row_l;
        const int grow = min(growu, M - 1);
        const int s = src_p[grow], d = dst_p[grow];
        const uint4 vl0 = *(const uint4*)(xlr + (size_t)s * 768 + gcol);
        const uint4 vl1 = *(const uint4*)(xlr + (size_t)s * 768 + gcol + 8);
        const uint4 vr0 = *(const uint4*)(xlr + (size_t)d * 768 + 384 + gcol);
        const uint4 vr1 = *(const uint4*)(xlr + (size_t)d * 768 + 384 + gcol + 8);

        // scatter this wave's 16x64 acc window into LDS (col ^ row<<2: conflict-free)
#pragma unroll
        for (int n = 0; n < 4; ++n)
#pragma unroll
            for (int r = 0; r < 4; ++r) {
                const int row = ((l >> 4) << 2) + r;
                const int col = (n << 4) + (l & 15);
                ep[(row << 6) + (col ^ (row << 2))] = acc[m][n][r];
            }
        // transposed read: lane owns one row, 16 contiguous cols (4x f32x4)
        float av[16];
#pragma unroll
        for (int k = 0; k < 4; ++k) {
            const int sc0 = (c0 + (k << 2)) ^ rswz;
            *(f32x4*)(av + 4 * k) = *(const f32x4*)(ep + (row_l << 6) + sc0);
        }
        const u32 lw[8] = {vl0.x, vl0.y, vl0.z, vl0.w, vl1.x, vl1.y, vl1.z, vl1.w};
        const u32 rw[8] = {vr0.x, vr0.y, vr0.z, vr0.w, vr1.x, vr1.y, vr1.z, vr1.w};
        float part = 0.f;
#pragma unroll
        for (int q = 0; q < 8; ++q) {
            float v0 = av[2 * q] + bf2f((unsigned short)(lw[q] & 0xffff)) +
                       bf2f((unsigned short)(rw[q] & 0xffff));
            float v1 = av[2 * q + 1] + bf2f((unsigned short)(lw[q] >> 16)) +
                       bf2f((unsigned short)(rw[q] >> 16));
            v0 = (v0 > 0.f) ? v0 : 0.2f * v0;
            v1 = (v1 > 0.f) ? v1 : 0.2f * v1;
            part += v0 * attv[2 * q] + v1 * attv[2 * q + 1];
        }
        part += __shfl_xor(part, 1, 64);  // combine the 2 half-head lanes
        if (growu < M && (l & 1) == 0)
            logits[(size_t)growu * HH + hbase + ((l & 2) >> 1)] = part;
    }
}

// ============ weight prep ============
__global__ void k_tw(const float* __restrict__ in, __hip_bfloat16* __restrict__ out, int nmat) {
    const size_t idx = (size_t)blockIdx.x * 256 + threadIdx.x;
    if (idx >= (size_t)nmat * DD * DD) return;
    const int m = idx / (DD * DD);
    const int rem = idx - (size_t)m * DD * DD;
    const int n = rem / DD, k = rem - n * DD;
    out[idx] = __float2bfloat16(in[(size_t)m * DD * DD + (size_t)k * DD + n]);
}

// fused Wl|Wr -> bf16 [L][768(n)][384(k)] transposed
__global__ void k_twlr(const float* __restrict__ Wl, const float* __restrict__ Wr,
                       __hip_bfloat16* __restrict__ out) {
    const size_t idx = (size_t)blockIdx.x * 256 + threadIdx.x;
    if (idx >= (size_t)LL * 768 * DD) return;
    const int i = idx / (768 * DD);
    const int rem = idx - (size_t)i * 768 * DD;
    const int n = rem / DD, k = rem - n * DD;
    const float v = (n < DD) ? Wl[(size_t)i * DD * DD + (size_t)k * DD + n]
                             : Wr[(size_t)i * DD * DD + (size_t)k * DD + (n - DD)];
    out[idx] = __float2bfloat16(v);
}

__global__ void k_blr(const float* __restrict__ bl, const float* __restrict__ br,
                      float* __restrict__ blr) {
    const int idx = blockIdx.x * 256 + threadIdx.x;
    if (idx >= LL * 768) return;
    const int i = idx / 768, c = idx - i * 768;
    blr[idx] = (c < DD) ? bl[i * DD + c] : br[i * DD + c - DD];
}

// eW1 f32 [100][384] -> bf16 [384][128] transposed, k>=100 zero-padded
__global__ void k_tw1(const float* __restrict__ in, __hip_bfloat16* __restrict__ out) {
    const int idx = blockIdx.x * 256 + threadIdx.x;
    if (idx >= DD * 128) return;
    const int n = idx >> 7, k = idx & 127;
    out[idx] = __float2bfloat16(k < NRBF ? in[(size_t)k * DD + n] : 0.f);
}

// ============ RBF features (CSR-permuted edge order), padded K=128, bf16 ============
__global__ __launch_bounds__(256) void k_rbf_chunk(const float* __restrict__ pos,
                                                   const int* __restrict__ src_p,
                                                   const int* __restrict__ dst_p,
                                                   int e0, int cm,
                                                   __hip_bfloat16* __restrict__ rbfp) {
    const int el = blockIdx.x * 2 + (threadIdx.x >> 7);
    if (el >= cm) return;
    const int e = e0 + el;
    const int c = threadIdx.x & 127;
    const int s = src_p[e], d = dst_p[e];
    const float dx = pos[s * 3 + 0] - pos[d * 3 + 0];
    const float dy = pos[s * 3 + 1] - pos[d * 3 + 1];
    const float dz = pos[s * 3 + 2] - pos[d * 3 + 2];
    const float dist = sqrtf(dx * dx + dy * dy + dz * dz);
    const float spacing = 30.f / 99.f;
    const float gamma = 1.f / (spacing * spacing + 1e-8f);
    float v = 0.f;
    if (c < NRBF) {
        const float dd = dist - (float)c * spacing;
        v = __expf(-gamma * dd * dd);
    }
    rbfp[(size_t)el * 128 + c] = __float2bfloat16(v);
}

// ============ in-place row LayerNorm on bf16 [rows][384]; one wave per row ============
__global__ __launch_bounds__(512) void k_ln_rows(__hip_bfloat16* __restrict__ u,
                                                 const float* __restrict__ g,
                                                 const float* __restrict__ be) {
    const int w = threadIdx.x >> 6, l = threadIdx.x & 63;
    const int row = blockIdx.x * 8 + w;
    float vals[8];
    float s = 0.f, q = 0.f;
    if (l < 48) {
        const uint4 vu = *(const uint4*)(u + (size_t)row * DD + 8 * l);
        const unsigned int* uw = (const unsigned int*)&vu;
#pragma unroll
        for (int i = 0; i < 4; ++i) {
            vals[2 * i] = bf2f((unsigned short)(uw[i] & 0xffff));
            vals[2 * i + 1] = bf2f((unsigned short)(uw[i] >> 16));
        }
#pragma unroll
        for (int i = 0; i < 8; ++i) { s += vals[i]; q += vals[i] * vals[i]; }
    }
#pragma unroll
    for (int off = 1; off < 64; off <<= 1) {
        s += __shfl_xor(s, off, 64);
        q += __shfl_xor(q, off, 64);
    }
    const float mu = s / DD;
    const float rs = rsqrtf(q / DD - mu * mu + 1e-5f);
    if (l < 48) {
        unsigned int ow[4];
        const float4 g0 = *(const float4*)(g + 8 * l);
        const float4 g1 = *(const float4*)(g + 8 * l + 4);
        const float4 b0 = *(const float4*)(be + 8 * l);
        const float4 b1 = *(const float4*)(be + 8 * l + 4);
        const float gv[8] = {g0.x, g0.y, g0.z, g0.w, g1.x, g1.y, g1.z, g1.w};
        const float bv[8] = {b0.x, b0.y, b0.z, b0.w, b1.x, b1.y, b1.z, b1.w};
#pragma unroll
        for (int i = 0; i < 4; ++i) {
            const float y0 = (vals[2 * i] - mu) * rs * gv[2 * i] + bv[2 * i];
            const float y1 = (vals[2 * i + 1] - mu) * rs * gv[2 * i + 1] + bv[2 * i + 1];
            const unsigned short h0 = __bfloat16_as_ushort(__float2bfloat16(y0));
            const unsigned short h1 = __bfloat16_as_ushort(__float2bfloat16(y1));
            ow[i] = (unsigned int)h0 | ((unsigned int)h1 << 16);
        }
        *(uint4*)(u + (size_t)row * DD + 8 * l) = *(uint4*)ow;
    }
}

// ============ node embedding ============
__global__ __launch_bounds__(384) void k_node_embed(const float* __restrict__ x,
                                                    const float* __restrict__ W,
                                                    const float* __restrict__ b,
                                                    const float* __restrict__ g,
                                                    const float* __restrict__ be,
                                                    float* __restrict__ h,
                                                    __hip_bfloat16* __restrict__ hb) {
    const int n = blockIdx.x, j = threadIdx.x;
    __shared__ float xrow[20];
    __shared__ float red[12];
    if (j < 20) xrow[j] = x[n * 20 + j];
    __syncthreads();
    float acc = b[j];
#pragma unroll
    for (int k = 0; k < 20; ++k) acc += xrow[k] * W[k * DD + j];
    float s = acc, q = acc * acc;
#pragma unroll
    for (int off = 32; off > 0; off >>= 1) {
        s += __shfl_down(s, off, 64);
        q += __shfl_down(q, off, 64);
    }
    const int wid = j >> 6;
    if ((j & 63) == 0) { red[wid] = s; red[6 + wid] = q; }
    __syncthreads();
    if (j == 0) {
        float ts = 0.f, tq = 0.f;
        for (int w = 0; w < 6; ++w) { ts += red[w]; tq += red[6 + w]; }
        float mu = ts / DD;
        red[0] = mu; red[6] = tq / DD - mu * mu;
    }
    __syncthreads();
    const float mu = red[0], var = red[6];
    float y = (acc - mu) * rsqrtf(var + 1e-5f) * g[j] + be[j];
    y = siluf(y);
    h[(size_t)n * DD + j] = y;
    hb[(size_t)n * DD + j] = __float2bfloat16(y);
}

// ============ CSR build over dst ============
__global__ void k_deg(const int* __restrict__ ei, int* __restrict__ deg) {
    int e = blockIdx.x * blockDim.x + threadIdx.x;
    if (e < EE) atomicAdd(&deg[ei[EE + e]], 1);
}

__global__ __launch_bounds__(1024) void k_scan(const int* __restrict__ deg, int* __restrict__ rp) {
    __shared__ int buf[1024];
    __shared__ int carry_s;
    const int tid = threadIdx.x;
    if (tid == 0) carry_s = 0;
    __syncthreads();
    for (int base = 0; base < NN; base += 1024) {
        int v = (base + tid < NN) ? deg[base + tid] : 0;
        buf[tid] = v;
        __syncthreads();
        for (int off = 1; off < 1024; off <<= 1) {
            int t = (tid >= off) ? buf[tid - off] : 0;
            __syncthreads();
            buf[tid] += t;
            __syncthreads();
        }
        const int incl = buf[tid];
        const int carry = carry_s;
        if (base + tid < NN) rp[base + tid] = carry + incl - v;
        __syncthreads();
        if (tid == 1023) carry_s = carry + incl;
        __syncthreads();
    }
    if (tid == 0) rp[NN] = carry_s;
}

__global__ void k_scatter(const int* __restrict__ ei, const int* __restrict__ rp,
                          int* __restrict__ cursor, int* __restrict__ col_e) {
    int e = blockIdx.x * blockDim.x + threadIdx.x;
    if (e < EE) {
        int d = ei[EE + e];
        int p = atomicAdd(&cursor[d], 1);
        col_e[rp[d] + p] = e;
    }
}

// p -> original edge col_e[p]; materialize permuted src/dst
__global__ void k_perm(const int* __restrict__ ei, const int* __restrict__ col_e,
                       int* __restrict__ src_p, int* __restrict__ dst_p) {
    int p = blockIdx.x * blockDim.x + threadIdx.x;
    if (p < EE) {
        const int e = col_e[p];
        src_p[p] = ei[e];
        dst_p[p] = ei[EE + e];
    }
}

// ============ per-node softmax + aggregate + BN + silu + residual ============
__global__ __launch_bounds__(256) void k_node_aggr(const float* __restrict__ logits,
                                                   const __hip_bfloat16* __restrict__ xlr,
                                                   const int* __restrict__ src_p,
                                                   const int* __restrict__ rp,
                                                   const float* __restrict__ cb_i,
                                                   const float* __restrict__ g_i,
                                                   const float* __restrict__ b_i,
                                                   const float* __restrict__ m_i,
                                                   const float* __restrict__ v_i,
                                                   float* __restrict__ h,
                                                   __hip_bfloat16* __restrict__ hb) {
    const int wv = threadIdx.x >> 6, l = threadIdx.x & 63;
    const int n = blockIdx.x * 4 + wv;
    if (n >= NN) return;
    const int beg = rp[n], end = rp[n + 1];

    float mx = -INFINITY, sum = 0.f;
    if (l < HH) {
        for (int i = beg; i < end; ++i) mx = fmaxf(mx, logits[(size_t)i * HH + l]);
        for (int i = beg; i < end; ++i) sum += __expf(logits[(size_t)i * HH + l] - mx);
    }
    const int head = (l < 48) ? (l >> 2) : 0;
    const float m_h = __shfl(mx, head, 64);
    const float inv_h = 1.f / (__shfl(sum, head, 64) + 1e-16f);

    if (l >= 48) return;
    const int c0 = l * 8;
    float acc[8] = {};
    for (int i = beg; i < end; ++i) {
        const float a = __expf(logits[(size_t)i * HH + head] - m_h) * inv_h;
        const int s = src_p[i];
        const uint4 vx = *(const uint4*)(xlr + (size_t)s * 768 + c0);
        const u32* xw = (const u32*)&vx;
#pragma unroll
        for (int q = 0; q < 4; ++q) {
            acc[2 * q]     += bf2f((unsigned short)(xw[q] & 0xffff)) * a;
            acc[2 * q + 1] += bf2f((unsigned short)(xw[q] >> 16)) * a;
        }
    }
    const float4 cb0 = *(const float4*)(cb_i + c0), cb1 = *(const float4*)(cb_i + c0 + 4);
    const float4 gg0 = *(const float4*)(g_i + c0),  gg1 = *(const float4*)(g_i + c0 + 4);
    const float4 bb0 = *(const float4*)(b_i + c0),  bb1 = *(const float4*)(b_i + c0 + 4);
    const float4 mm0 = *(const float4*)(m_i + c0),  mm1 = *(const float4*)(m_i + c0 + 4);
    const float4 vv0 = *(const float4*)(v_i + c0),  vv1 = *(const float4*)(v_i + c0 + 4);
    const float cbv[8] = {cb0.x, cb0.y, cb0.z, cb0.w, cb1.x, cb1.y, cb1.z, cb1.w};
    const float gv[8]  = {gg0.x, gg0.y, gg0.z, gg0.w, gg1.x, gg1.y, gg1.z, gg1.w};
    const float bv[8]  = {bb0.x, bb0.y, bb0.z, bb0.w, bb1.x, bb1.y, bb1.z, bb1.w};
    const float mv[8]  = {mm0.x, mm0.y, mm0.z, mm0.w, mm1.x, mm1.y, mm1.z, mm1.w};
    const float vvv[8] = {vv0.x, vv0.y, vv0.z, vv0.w, vv1.x, vv1.y, vv1.z, vv1.w};
    float4 h0 = *(const float4*)(h + (size_t)n * DD + c0);
    float4 h1 = *(const float4*)(h + (size_t)n * DD + c0 + 4);
    float hv[8] = {h0.x, h0.y, h0.z, h0.w, h1.x, h1.y, h1.z, h1.w};
    unsigned int ow[4];
#pragma unroll
    for (int q = 0; q < 8; ++q) {
        float o = acc[q] + cbv[q];
        o = (o - mv[q]) * rsqrtf(vvv[q] + 1e-5f) * gv[q] + bv[q];
        hv[q] = siluf(o) + hv[q];
    }
#pragma unroll
    for (int q = 0; q < 4; ++q) {
        const unsigned short b0 = __bfloat16_as_ushort(__float2bfloat16(hv[2 * q]));
        const unsigned short b1 = __bfloat16_as_ushort(__float2bfloat16(hv[2 * q + 1]));
        ow[q] = (unsigned int)b0 | ((unsigned int)b1 << 16);
    }
    *(float4*)(h + (size_t)n * DD + c0) = make_float4(hv[0], hv[1], hv[2], hv[3]);
    *(float4*)(h + (size_t)n * DD + c0 + 4) = make_float4(hv[4], hv[5], hv[6], hv[7]);
    *(uint4*)(hb + (size_t)n * DD + c0) = *(uint4*)ow;
}

// ============ pooling: segmented (batch sorted) ============
__global__ void k_fill(float* __restrict__ p, float v, int n) {
    int i = blockIdx.x * blockDim.x + threadIdx.x;
    if (i < n) p[i] = v;
}

__global__ __launch_bounds__(384) void k_pool2(const float* __restrict__ h,
                                               const int* __restrict__ batch,
                                               float* __restrict__ gsum,
                                               float* __restrict__ gmax,
                                               float* __restrict__ gcnt) {
    const int j = threadIdx.x;
    const int n0 = blockIdx.x * 256;
    const int n1 = min(n0 + 256, NN);
    int cur = batch[n0];
    float s = 0.f, mx = -INFINITY;
    int cnt = 0;
    for (int n = n0; n < n1; ++n) {
        const int g = batch[n];
        if (g != cur) {
            atomicAdd(&gsum[cur * DD + j], s);
            atomicMaxF(&gmax[cur * DD + j], mx);
            if (j == 0) atomicAdd(&gcnt[cur], (float)cnt);
            s = 0.f; mx = -INFINITY; cnt = 0; cur = g;
        }
        const float v = h[(size_t)n * DD + j];
        s += v; mx = fmaxf(mx, v); ++cnt;
    }
    atomicAdd(&gsum[cur * DD + j], s);
    atomicMaxF(&gmax[cur * DD + j], mx);
    if (j == 0) atomicAdd(&gcnt[cur], (float)cnt);
}

// ============ per-graph MLP head (fp32 output) ============
__global__ __launch_bounds__(384) void k_head(const float* __restrict__ gsum,
                                              const float* __restrict__ gmax,
                                              const float* __restrict__ gcnt,
                                              const float* __restrict__ pW,
                                              const float* __restrict__ pb,
                                              const float* __restrict__ hW1,
                                              const float* __restrict__ hb1,
                                              const float* __restrict__ hW2,
                                              const float* __restrict__ hb2,
                                              const float* __restrict__ hW3,
                                              const float* __restrict__ hb3,
                                              float* __restrict__ out) {
    const int g = blockIdx.x, j = threadIdx.x;
    __shared__ float hg[2 * DD];
    __shared__ float p1[DD];
    __shared__ float p2[DD];
    __shared__ float p3[DD / 2];
    __shared__ float red[6];
    const float cnt = fmaxf(gcnt[g], 1.f);
    hg[j] = gsum[g * DD + j] / cnt;
    hg[DD + j] = gmax[g * DD + j];
    __syncthreads();
    float a = pb[j];
    for (int k = 0; k < 2 * DD; ++k) a += hg[k] * pW[(size_t)k * DD + j];
    p1[j] = siluf(a);
    __syncthreads();
    a = hb1[j];
    for (int k = 0; k < DD; ++k) a += p1[k] * hW1[(size_t)k * DD + j];
    p2[j] = siluf(a);
    __syncthreads();
    if (j < DD / 2) {
        a = hb2[j];
        for (int k = 0; k < DD; ++k) a += p2[k] * hW2[(size_t)k * (DD / 2) + j];
        p3[j] = siluf(a);
    }
    __syncthreads();
    float v = (j < DD / 2) ? p3[j] * hW3[j] : 0.f;
#pragma unroll
    for (int off = 32; off > 0; off >>= 1) v += __shfl_down(v, off, 64);
    if ((j & 63) == 0) red[j >> 6] = v;
    __syncthreads();
    if (j == 0) {
        float s = 0.f;
        for (int w = 0; w < 6; ++w) s += red[w];
        out[g] = s + hb3[0];
    }
}

static inline int gemm_grid(int M, int N) {
    const int nr = (M + 127) >> 7, nc = N >> 7;
    return ((nr + 7) >> 3) * nc * 8;
}

extern "C" void kernel_launch(void* const* d_in, const int* in_sizes, int n_in,
                              void* d_out, int out_size, void* d_ws, size_t ws_size,
                              hipStream_t stream) {
    (void)in_sizes; (void)n_in; (void)out_size; (void)ws_size;
    const float* x      = (const float*)d_in[0];
    const float* pos    = (const float*)d_in[1];
    const int*   ei     = (const int*)d_in[2];
    const int*   batch  = (const int*)d_in[3];
    const float* emb_W  = (const float*)d_in[4];
    const float* emb_b  = (const float*)d_in[5];
    const float* emb_g  = (const float*)d_in[6];
    const float* emb_be = (const float*)d_in[7];
    const float* eW1    = (const float*)d_in[8];
    const float* eb1    = (const float*)d_in[9];
    const float* eW2    = (const float*)d_in[10];
    const float* eb2    = (const float*)d_in[11];
    const float* e_g    = (const float*)d_in[12];
    const float* e_be   = (const float*)d_in[13];
    const float* Wl     = (const float*)d_in[14];
    const float* bl     = (const float*)d_in[15];
    const float* Wr     = (const float*)d_in[16];
    const float* br     = (const float*)d_in[17];
    const float* We     = (const float*)d_in[18];
    const float* att    = (const float*)d_in[19];
    const float* cb     = (const float*)d_in[20];
    const float* bn_g   = (const float*)d_in[21];
    const float* bn_b   = (const float*)d_in[22];
    const float* bn_m   = (const float*)d_in[23];
    const float* bn_v   = (const float*)d_in[24];
    const float* pW     = (const float*)d_in[25];
    const float* pb     = (const float*)d_in[26];
    const float* hW1    = (const float*)d_in[27];
    const float* hb1    = (const float*)d_in[28];
    const float* hW2    = (const float*)d_in[29];
    const float* hb2    = (const float*)d_in[30];
    const float* hW3    = (const float*)d_in[31];
    const float* hb3    = (const float*)d_in[32];

    char* wp = (char*)d_ws;
    auto carve = [&](size_t bytes) -> void* {
        void* p = (void*)wp;
        wp += (bytes + 255) & ~(size_t)255;
        return p;
    };
    float* h      = (float*)carve((size_t)NN * DD * 4);
    __hip_bfloat16* hbf = (__hip_bfloat16*)carve((size_t)NN * DD * 2);
    __hip_bfloat16* xlr = (__hip_bfloat16*)carve((size_t)NN * 768 * 2);
    __hip_bfloat16* ebf = (__hip_bfloat16*)carve((size_t)EE * DD * 2);
    float* logits = (float*)carve((size_t)EE * HH * 4);
    int* deg      = (int*)carve((size_t)NN * 4);
    int* cursor   = (int*)carve((size_t)NN * 4);
    int* rp       = (int*)carve((size_t)(NN + 1) * 4);
    int* col_e    = (int*)carve((size_t)EE * 4);
    int* src_p    = (int*)carve((size_t)EE * 4);
    int* dst_p    = (int*)carve((size_t)EE * 4);
    float* gsum   = (float*)carve((size_t)GG * DD * 4);
    float* gmax   = (float*)carve((size_t)GG * DD * 4);
    float* gcnt   = (float*)carve((size_t)GG * 4);
    __hip_bfloat16* Wlrt = (__hip_bfloat16*)carve((size_t)LL * 768 * DD * 2);
    __hip_bfloat16* Wet  = (__hip_bfloat16*)carve((size_t)LL * DD * DD * 2);
    float* blr    = (float*)carve((size_t)LL * 768 * 4);
    __hip_bfloat16* eW1t = (__hip_bfloat16*)carve((size_t)DD * 128 * 2);
    __hip_bfloat16* eW2t = (__hip_bfloat16*)carve((size_t)DD * DD * 2);

    __hip_bfloat16* rbfc = (__hip_bfloat16*)logits;  // CHUNK*128*2 = 8.39 MB <= 9.6 MB
    __hip_bfloat16* tc   = xlr;                      // CHUNK*384*2 = 25.2 MB <= 30.7 MB

    hipMemsetAsync(deg, 0, (size_t)NN * 4, stream);
    hipMemsetAsync(cursor, 0, (size_t)NN * 4, stream);

    // ---- weight prep ----
    {
        const int nblkLR = (int)(((size_t)LL * 768 * DD + 255) / 256);
        const int nblk6 = (int)(((size_t)LL * DD * DD + 255) / 256);
        k_twlr<<<nblkLR, 256, 0, stream>>>(Wl, Wr, Wlrt);
        k_tw<<<nblk6, 256, 0, stream>>>(We, Wet, LL);
        k_blr<<<(LL * 768 + 255) / 256, 256, 0, stream>>>(bl, br, blr);
        k_tw<<<(DD * DD + 255) / 256, 256, 0, stream>>>(eW2, eW2t, 1);
        k_tw1<<<(DD * 128 + 255) / 256, 256, 0, stream>>>(eW1, eW1t);
    }

    // ---- node embedding ----
    k_node_embed<<<NN, 384, 0, stream>>>(x, emb_W, emb_b, emb_g, emb_be, h, hbf);

    // ---- CSR + edge permutation ----
    k_deg<<<(EE + 255) / 256, 256, 0, stream>>>(ei, deg);
    k_scan<<<1, 1024, 0, stream>>>(deg, rp);
    k_scatter<<<(EE + 255) / 256, 256, 0, stream>>>(ei, rp, cursor, col_e);
    k_perm<<<(EE + 255) / 256, 256, 0, stream>>>(ei, col_e, src_p, dst_p);

    // ---- edge encoder (chunked, CSR order): rbf -> t -> ebf, then LN in-place ----
    for (int c0 = 0; c0 < EE; c0 += CHUNK) {
        const int cm = (EE - c0 < CHUNK) ? (EE - c0) : CHUNK;
        k_rbf_chunk<<<(cm + 1) / 2, 256, 0, stream>>>(pos, src_p, dst_p, c0, cm, rbfc);
        k_gemm_bt<true, true><<<gemm_grid(cm, DD), 256, 0, stream>>>(rbfc, eW1t, eb1, tc, cm, DD, 128);
        k_gemm_bt<true, false><<<gemm_grid(cm, DD), 256, 0, stream>>>(tc, eW2t, eb2,
                                                                      ebf + (size_t)c0 * DD, cm, DD, DD);
    }
    k_ln_rows<<<EE / 8, 512, 0, stream>>>(ebf, e_g, e_be);

    // ---- layers ----
    for (int i = 0; i < LL; ++i) {
        const __hip_bfloat16* Wlrt_i = Wlrt + (size_t)i * 768 * DD;
        const __hip_bfloat16* Wet_i  = Wet + (size_t)i * DD * DD;
        const float* blr_i = blr + (size_t)i * 768;
        const float* att_i = att + (size_t)i * HH * CC;
        const float* cb_i  = cb + (size_t)i * DD;
        const float* bng_i = bn_g + (size_t)i * DD;
        const float* bnb_i = bn_b + (size_t)i * DD;
        const float* bnm_i = bn_m + (size_t)i * DD;
        const float* bnv_i = bn_v + (size_t)i * DD;

        k_gemm_bt<true, false><<<gemm_grid(NN, 768), 256, 0, stream>>>(hbf, Wlrt_i, blr_i, xlr,
                                                                       NN, 768, DD);
        k_gemm_attn<<<gemm_grid(EE, DD), 256, 0, stream>>>(ebf, Wet_i, xlr, src_p, dst_p,
                                                           att_i, logits, EE, DD);
        k_node_aggr<<<(NN + 3) / 4, 256, 0, stream>>>(logits, xlr, src_p, rp, cb_i, bng_i, bnb_i,
                                                      bnm_i, bnv_i, h, hbf);
    }

    // ---- pooling + head ----
    hipMemsetAsync(gsum, 0, (size_t)GG * DD * 4, stream);
    hipMemsetAsync(gcnt, 0, (size_t)GG * 4, stream);
    k_fill<<<(GG * DD + 255) / 256, 256, 0, stream>>>(gmax, -INFINITY, GG * DD);
    k_pool2<<<(NN + 255) / 256, 384, 0, stream>>>(h, batch, gsum, gmax, gcnt);
    k_head<<<GG, 384, 0, stream>>>(gsum, gmax, gcnt, pW, pb, hW1, hb1, hW2, hb2, hW3, hb3,
                                   (float*)d_out);
}

// Round 11
// 1842.173 us; speedup vs baseline: 1.0296x; 1.0296x over previous
//
#include <hip/hip_runtime.h>
#include <hip/hip_bf16.h>
#include <math.h>

#define NN 20000
#define EE 200000
#define GG 32
#define DD 384
#define HH 12
#define CC 32
#define LL 6
#define NRBF 100
#define CHUNK 32768

typedef short s16x8 __attribute__((ext_vector_type(8)));
typedef float f32x4 __attribute__((ext_vector_type(4)));
typedef unsigned int u32;

__device__ __forceinline__ float siluf(float x) { return x / (1.f + __expf(-x)); }
__device__ __forceinline__ float bf2f(unsigned short u) {
    return __uint_as_float(((unsigned int)u) << 16);
}

__device__ __forceinline__ void atomicMaxF(float* addr, float val) {
    if (val >= 0.f) atomicMax((int*)addr, __float_as_int(val));
    else atomicMin((unsigned int*)addr, __float_as_uint(val));
}

// async global->LDS, 16B per lane; LDS dest = wave-uniform base + lane*16
__device__ __forceinline__ void gload16(const void* g, void* l) {
    __builtin_amdgcn_global_load_lds((const __attribute__((address_space(1))) u32*)g,
                                     (__attribute__((address_space(3))) u32*)l, 16, 0, 0);
}

// XCD-aware tile decode: col-tiles of one row-tile run consecutively on ONE XCD
// (dispatch round-robins XCDs by linear workgroup id) -> A row-tile stays L2-hot,
// A read from HBM exactly once (verified round 7: FETCH 301->156 MB).
__device__ __forceinline__ bool tile_decode(int NC, int nrows, int& rowt, int& col) {
    const int t = blockIdx.x;
    const int q = t >> 3;
    col = q % NC;
    rowt = (q / NC) * 8 + (t & 7);
    return rowt < nrows;
}

// Symbol the harness template named; defined for safety, never launched.
__global__ void EquivariantProteinGNN_45552423141948_kernel() {}

// ---- shared BK=32 K-loop (128x128 tile, 4 waves, 16KB As + 16KB Bs).
// BK=64 tried in round 9: occupancy 31%->21%, net regression -> reverted (m132 analog).
// LDS row = 64B = 4 chunks of 16B, chunk-swizzled c ^= (row>>1)&3 via pre-swizzled
// global SOURCE + swizzled READ (same involution both sides; linear gload_lds dest).
__device__ __forceinline__ void gemm_kloop(const __hip_bfloat16* __restrict__ A,
                                           const __hip_bfloat16* __restrict__ Bt,
                                           int M, int K, int m0, int n0,
                                           unsigned short* As, unsigned short* Bs,
                                           f32x4 (&acc)[4][4]) {
    char* AsB = (char*)As;
    char* BsB = (char*)Bs;
    const int t = threadIdx.x;
    const int w = t >> 6, l = t & 63;
    const int wr = w >> 1, wc = w & 1;

    const int seg0 = 2 * w, seg1 = seg0 + 1;
    const int r0s = seg0 * 16 + (l >> 2);
    const int r1s = seg1 * 16 + (l >> 2);
    const int cg0 = (l & 3) ^ ((r0s >> 1) & 3);
    const int cg1 = (l & 3) ^ ((r1s >> 1) & 3);
    const size_t aSrc0 = (size_t)min(m0 + r0s, M - 1) * K + cg0 * 8;
    const size_t aSrc1 = (size_t)min(m0 + r1s, M - 1) * K + cg1 * 8;
    const size_t bSrc0 = (size_t)(n0 + r0s) * K + cg0 * 8;
    const size_t bSrc1 = (size_t)(n0 + r1s) * K + cg1 * 8;
    unsigned short* AsW0 = As + seg0 * 512;
    unsigned short* AsW1 = As + seg1 * 512;
    unsigned short* BsW0 = Bs + seg0 * 512;
    unsigned short* BsW1 = Bs + seg1 * 512;

    int aoff[4], boff[4];
#pragma unroll
    for (int m = 0; m < 4; ++m) {
        const int row = wr * 64 + m * 16 + (l & 15);
        aoff[m] = row * 64 + ((((l >> 4)) ^ ((row >> 1) & 3)) << 4);
        const int rowb = wc * 64 + m * 16 + (l & 15);
        boff[m] = rowb * 64 + ((((l >> 4)) ^ ((rowb >> 1) & 3)) << 4);
    }

    for (int kk = 0; kk < K; kk += 32) {
        __syncthreads();
        gload16(A + aSrc0 + kk, AsW0);
        gload16(A + aSrc1 + kk, AsW1);
        gload16(Bt + bSrc0 + kk, BsW0);
        gload16(Bt + bSrc1 + kk, BsW1);
        __syncthreads();
        s16x8 af[4], bfr[4];
#pragma unroll
        for (int m = 0; m < 4; ++m) af[m] = *(const s16x8*)(AsB + aoff[m]);
#pragma unroll
        for (int n = 0; n < 4; ++n) bfr[n] = *(const s16x8*)(BsB + boff[n]);
#pragma unroll
        for (int m = 0; m < 4; ++m)
#pragma unroll
            for (int n = 0; n < 4; ++n)
                acc[m][n] = __builtin_amdgcn_mfma_f32_16x16x32_bf16(af[m], bfr[n], acc[m][n], 0, 0, 0);
    }
}

// ============ bf16 MFMA GEMM: C[M][N] = A[M][K] @ Bt[N][K]^T (+bias)(+silu) -> bf16 ============
template<bool BIAS, bool SILU>
__global__ __launch_bounds__(256) void k_gemm_bt(const __hip_bfloat16* __restrict__ A,
                                                 const __hip_bfloat16* __restrict__ Bt,
                                                 const float* __restrict__ bias,
                                                 __hip_bfloat16* __restrict__ Cmat,
                                                 int M, int N, int K) {
    int rowt, colt;
    if (!tile_decode(N >> 7, (M + 127) >> 7, rowt, colt)) return;
    const int m0 = rowt << 7, n0 = colt << 7;

    __shared__ unsigned short As[128 * 32];
    __shared__ unsigned short Bs[128 * 32];
    const int l = threadIdx.x & 63;
    const int w = threadIdx.x >> 6;
    const int wr = w >> 1, wc = w & 1;

    f32x4 acc[4][4] = {};
    gemm_kloop(A, Bt, M, K, m0, n0, As, Bs, acc);

#pragma unroll
    for (int n = 0; n < 4; ++n) {
        const int col = n0 + wc * 64 + n * 16 + (l & 15);
        const float bv = BIAS ? bias[col] : 0.f;
#pragma unroll
        for (int m = 0; m < 4; ++m) {
            const int rbase = m0 + wr * 64 + m * 16 + ((l >> 4) << 2);
#pragma unroll
            for (int r = 0; r < 4; ++r) {
                const int row = rbase + r;
                if (row < M) {
                    float v = acc[m][n][r] + bv;
                    if (SILU) v = siluf(v);
                    Cmat[(size_t)row * N + col] = __float2bfloat16(v);
                }
            }
        }
    }
}

// ===== fused: ee = ebf @ Wet^T, then logits[p][h] over CSR-ordered edges =====
// Epilogue via per-wave LDS transpose (aliases As/Bs). Swizzle col^(row<<2):
// verified 0 bank conflicts in round-9/10 counters. Gathers issued BEFORE the LDS
// scatter so their latency hides under the ds_write/ds_read work.
__global__ __launch_bounds__(256) void k_gemm_attn(const __hip_bfloat16* __restrict__ A,
                                                   const __hip_bfloat16* __restrict__ Bt,
                                                   const __hip_bfloat16* __restrict__ xlr,
                                                   const int* __restrict__ src_p,
                                                   const int* __restrict__ dst_p,
                                                   const float* __restrict__ att_i,
                                                   float* __restrict__ logits,
                                                   int M, int K) {
    int rowt, colt;
    if (!tile_decode(DD >> 7, (M + 127) >> 7, rowt, colt)) return;
    const int m0 = rowt << 7, n0 = colt << 7;

    __shared__ char smem[16384];
    unsigned short* As = (unsigned short*)smem;
    unsigned short* Bs = (unsigned short*)(smem + 8192);
    const int l = threadIdx.x & 63;
    const int w = threadIdx.x >> 6;
    const int wr = w >> 1, wc = w & 1;

    f32x4 acc[4][4] = {};
    gemm_kloop(A, Bt, M, K, m0, n0, As, Bs, acc);

    __syncthreads();  // all waves done with As/Bs; reuse as per-wave epilogue scratch

    // ---- LDS-transpose epilogue ----
    float* ep = (float*)(smem + w * 4096);  // per-wave 16x64 f32
    const int row_l = l >> 2;               // 0..15: local edge row this lane reduces
    const int c0 = (l & 3) << 4;            // 16-col slice within the 64-col window
    const int gcol = n0 + wc * 64 + c0;
    const int hbase = (n0 + wc * 64) >> 5;  // first of 2 heads in this wave's window
    const int rswz = row_l << 2;

    float attv[16];
#pragma unroll
    for (int k = 0; k < 4; ++k)
        *(float4*)(attv + 4 * k) = *(const float4*)(att_i + gcol + 4 * k);

#pragma unroll
    for (int m = 0; m < 4; ++m) {
        // issue independent gathers FIRST (latency hides under the LDS transpose)
        const int growu = m0 + wr * 64 + m * 16 + row_l;
        const int grow = min(growu, M - 1);
        const int s = src_p[grow], d = dst_p[grow];
        const uint4 vl0 = *(const uint4*)(xlr + (size_t)s * 768 + gcol);
        const uint4 vl1 = *(const uint4*)(xlr + (size_t)s * 768 + gcol + 8);
        const uint4 vr0 = *(const uint4*)(xlr + (size_t)d * 768 + 384 + gcol);
        const uint4 vr1 = *(const uint4*)(xlr + (size_t)d * 768 + 384 + gcol + 8);

        // scatter this wave's 16x64 acc window into LDS (col ^ row<<2: conflict-free)
#pragma unroll
        for (int n = 0; n < 4; ++n)
#pragma unroll
            for (int r = 0; r < 4; ++r) {
                const int row = ((l >> 4) << 2) + r;
                const int col = (n << 4) + (l & 15);
                ep[(row << 6) + (col ^ (row << 2))] = acc[m][n][r];
            }
        // transposed read: lane owns one row, 16 contiguous cols (4x f32x4)
        float av[16];
#pragma unroll
        for (int k = 0; k < 4; ++k) {
            const int sc0 = (c0 + (k << 2)) ^ rswz;
            *(f32x4*)(av + 4 * k) = *(const f32x4*)(ep + (row_l << 6) + sc0);
        }
        const u32 lw[8] = {vl0.x, vl0.y, vl0.z, vl0.w, vl1.x, vl1.y, vl1.z, vl1.w};
        const u32 rw[8] = {vr0.x, vr0.y, vr0.z, vr0.w, vr1.x, vr1.y, vr1.z, vr1.w};
        float part = 0.f;
#pragma unroll
        for (int q = 0; q < 8; ++q) {
            float v0 = av[2 * q] + bf2f((unsigned short)(lw[q] & 0xffff)) +
                       bf2f((unsigned short)(rw[q] & 0xffff));
            float v1 = av[2 * q + 1] + bf2f((unsigned short)(lw[q] >> 16)) +
                       bf2f((unsigned short)(rw[q] >> 16));
            v0 = (v0 > 0.f) ? v0 : 0.2f * v0;
            v1 = (v1 > 0.f) ? v1 : 0.2f * v1;
            part += v0 * attv[2 * q] + v1 * attv[2 * q + 1];
        }
        part += __shfl_xor(part, 1, 64);  // combine the 2 half-head lanes
        if (growu < M && (l & 1) == 0)
            logits[(size_t)growu * HH + hbase + ((l & 2) >> 1)] = part;
    }
}

// ============ weight prep ============
__global__ void k_tw(const float* __restrict__ in, __hip_bfloat16* __restrict__ out, int nmat) {
    const size_t idx = (size_t)blockIdx.x * 256 + threadIdx.x;
    if (idx >= (size_t)nmat * DD * DD) return;
    const int m = idx / (DD * DD);
    const int rem = idx - (size_t)m * DD * DD;
    const int n = rem / DD, k = rem - n * DD;
    out[idx] = __float2bfloat16(in[(size_t)m * DD * DD + (size_t)k * DD + n]);
}

// fused Wl|Wr -> bf16 [L][768(n)][384(k)] transposed
__global__ void k_twlr(const float* __restrict__ Wl, const float* __restrict__ Wr,
                       __hip_bfloat16* __restrict__ out) {
    const size_t idx = (size_t)blockIdx.x * 256 + threadIdx.x;
    if (idx >= (size_t)LL * 768 * DD) return;
    const int i = idx / (768 * DD);
    const int rem = idx - (size_t)i * 768 * DD;
    const int n = rem / DD, k = rem - n * DD;
    const float v = (n < DD) ? Wl[(size_t)i * DD * DD + (size_t)k * DD + n]
                             : Wr[(size_t)i * DD * DD + (size_t)k * DD + (n - DD)];
    out[idx] = __float2bfloat16(v);
}

__global__ void k_blr(const float* __restrict__ bl, const float* __restrict__ br,
                      float* __restrict__ blr) {
    const int idx = blockIdx.x * 256 + threadIdx.x;
    if (idx >= LL * 768) return;
    const int i = idx / 768, c = idx - i * 768;
    blr[idx] = (c < DD) ? bl[i * DD + c] : br[i * DD + c - DD];
}

// eW1 f32 [100][384] -> bf16 [384][128] transposed, k>=100 zero-padded
__global__ void k_tw1(const float* __restrict__ in, __hip_bfloat16* __restrict__ out) {
    const int idx = blockIdx.x * 256 + threadIdx.x;
    if (idx >= DD * 128) return;
    const int n = idx >> 7, k = idx & 127;
    out[idx] = __float2bfloat16(k < NRBF ? in[(size_t)k * DD + n] : 0.f);
}

// ============ RBF features (CSR-permuted edge order), padded K=128, bf16 ============
__global__ __launch_bounds__(256) void k_rbf_chunk(const float* __restrict__ pos,
                                                   const int* __restrict__ src_p,
                                                   const int* __restrict__ dst_p,
                                                   int e0, int cm,
                                                   __hip_bfloat16* __restrict__ rbfp) {
    const int el = blockIdx.x * 2 + (threadIdx.x >> 7);
    if (el >= cm) return;
    const int e = e0 + el;
    const int c = threadIdx.x & 127;
    const int s = src_p[e], d = dst_p[e];
    const float dx = pos[s * 3 + 0] - pos[d * 3 + 0];
    const float dy = pos[s * 3 + 1] - pos[d * 3 + 1];
    const float dz = pos[s * 3 + 2] - pos[d * 3 + 2];
    const float dist = sqrtf(dx * dx + dy * dy + dz * dz);
    const float spacing = 30.f / 99.f;
    const float gamma = 1.f / (spacing * spacing + 1e-8f);
    float v = 0.f;
    if (c < NRBF) {
        const float dd = dist - (float)c * spacing;
        v = __expf(-gamma * dd * dd);
    }
    rbfp[(size_t)el * 128 + c] = __float2bfloat16(v);
}

// ============ in-place row LayerNorm on bf16 [rows][384]; one wave per row ============
__global__ __launch_bounds__(512) void k_ln_rows(__hip_bfloat16* __restrict__ u,
                                                 const float* __restrict__ g,
                                                 const float* __restrict__ be) {
    const int w = threadIdx.x >> 6, l = threadIdx.x & 63;
    const int row = blockIdx.x * 8 + w;
    float vals[8];
    float s = 0.f, q = 0.f;
    if (l < 48) {
        const uint4 vu = *(const uint4*)(u + (size_t)row * DD + 8 * l);
        const unsigned int* uw = (const unsigned int*)&vu;
#pragma unroll
        for (int i = 0; i < 4; ++i) {
            vals[2 * i] = bf2f((unsigned short)(uw[i] & 0xffff));
            vals[2 * i + 1] = bf2f((unsigned short)(uw[i] >> 16));
        }
#pragma unroll
        for (int i = 0; i < 8; ++i) { s += vals[i]; q += vals[i] * vals[i]; }
    }
#pragma unroll
    for (int off = 1; off < 64; off <<= 1) {
        s += __shfl_xor(s, off, 64);
        q += __shfl_xor(q, off, 64);
    }
    const float mu = s / DD;
    const float rs = rsqrtf(q / DD - mu * mu + 1e-5f);
    if (l < 48) {
        unsigned int ow[4];
        const float4 g0 = *(const float4*)(g + 8 * l);
        const float4 g1 = *(const float4*)(g + 8 * l + 4);
        const float4 b0 = *(const float4*)(be + 8 * l);
        const float4 b1 = *(const float4*)(be + 8 * l + 4);
        const float gv[8] = {g0.x, g0.y, g0.z, g0.w, g1.x, g1.y, g1.z, g1.w};
        const float bv[8] = {b0.x, b0.y, b0.z, b0.w, b1.x, b1.y, b1.z, b1.w};
#pragma unroll
        for (int i = 0; i < 4; ++i) {
            const float y0 = (vals[2 * i] - mu) * rs * gv[2 * i] + bv[2 * i];
            const float y1 = (vals[2 * i + 1] - mu) * rs * gv[2 * i + 1] + bv[2 * i + 1];
            const unsigned short h0 = __bfloat16_as_ushort(__float2bfloat16(y0));
            const unsigned short h1 = __bfloat16_as_ushort(__float2bfloat16(y1));
            ow[i] = (unsigned int)h0 | ((unsigned int)h1 << 16);
        }
        *(uint4*)(u + (size_t)row * DD + 8 * l) = *(uint4*)ow;
    }
}

// ============ node embedding ============
__global__ __launch_bounds__(384) void k_node_embed(const float* __restrict__ x,
                                                    const float* __restrict__ W,
                                                    const float* __restrict__ b,
                                                    const float* __restrict__ g,
                                                    const float* __restrict__ be,
                                                    float* __restrict__ h,
                                                    __hip_bfloat16* __restrict__ hb) {
    const int n = blockIdx.x, j = threadIdx.x;
    __shared__ float xrow[20];
    __shared__ float red[12];
    if (j < 20) xrow[j] = x[n * 20 + j];
    __syncthreads();
    float acc = b[j];
#pragma unroll
    for (int k = 0; k < 20; ++k) acc += xrow[k] * W[k * DD + j];
    float s = acc, q = acc * acc;
#pragma unroll
    for (int off = 32; off > 0; off >>= 1) {
        s += __shfl_down(s, off, 64);
        q += __shfl_down(q, off, 64);
    }
    const int wid = j >> 6;
    if ((j & 63) == 0) { red[wid] = s; red[6 + wid] = q; }
    __syncthreads();
    if (j == 0) {
        float ts = 0.f, tq = 0.f;
        for (int w = 0; w < 6; ++w) { ts += red[w]; tq += red[6 + w]; }
        float mu = ts / DD;
        red[0] = mu; red[6] = tq / DD - mu * mu;
    }
    __syncthreads();
    const float mu = red[0], var = red[6];
    float y = (acc - mu) * rsqrtf(var + 1e-5f) * g[j] + be[j];
    y = siluf(y);
    h[(size_t)n * DD + j] = y;
    hb[(size_t)n * DD + j] = __float2bfloat16(y);
}

// ============ CSR build over dst ============
__global__ void k_deg(const int* __restrict__ ei, int* __restrict__ deg) {
    int e = blockIdx.x * blockDim.x + threadIdx.x;
    if (e < EE) atomicAdd(&deg[ei[EE + e]], 1);
}

__global__ __launch_bounds__(1024) void k_scan(const int* __restrict__ deg, int* __restrict__ rp) {
    __shared__ int buf[1024];
    __shared__ int carry_s;
    const int tid = threadIdx.x;
    if (tid == 0) carry_s = 0;
    __syncthreads();
    for (int base = 0; base < NN; base += 1024) {
        int v = (base + tid < NN) ? deg[base + tid] : 0;
        buf[tid] = v;
        __syncthreads();
        for (int off = 1; off < 1024; off <<= 1) {
            int t = (tid >= off) ? buf[tid - off] : 0;
            __syncthreads();
            buf[tid] += t;
            __syncthreads();
        }
        const int incl = buf[tid];
        const int carry = carry_s;
        if (base + tid < NN) rp[base + tid] = carry + incl - v;
        __syncthreads();
        if (tid == 1023) carry_s = carry + incl;
        __syncthreads();
    }
    if (tid == 0) rp[NN] = carry_s;
}

__global__ void k_scatter(const int* __restrict__ ei, const int* __restrict__ rp,
                          int* __restrict__ cursor, int* __restrict__ col_e) {
    int e = blockIdx.x * blockDim.x + threadIdx.x;
    if (e < EE) {
        int d = ei[EE + e];
        int p = atomicAdd(&cursor[d], 1);
        col_e[rp[d] + p] = e;
    }
}

// p -> original edge col_e[p]; materialize permuted src/dst
__global__ void k_perm(const int* __restrict__ ei, const int* __restrict__ col_e,
                       int* __restrict__ src_p, int* __restrict__ dst_p) {
    int p = blockIdx.x * blockDim.x + threadIdx.x;
    if (p < EE) {
        const int e = col_e[p];
        src_p[p] = ei[e];
        dst_p[p] = ei[EE + e];
    }
}

// ============ per-node softmax + aggregate + BN + silu + residual ============
// Stats phase wave-parallelized (Common-mistake #6 fix): 4 lanes per head stride the
// edge list, then a 2-step shfl_xor reduce within each aligned 4-lane group. Serial
// chain len deg -> deg/4, and all 48 lanes stay busy; no broadcast needed after.
__global__ __launch_bounds__(256) void k_node_aggr(const float* __restrict__ logits,
                                                   const __hip_bfloat16* __restrict__ xlr,
                                                   const int* __restrict__ src_p,
                                                   const int* __restrict__ rp,
                                                   const float* __restrict__ cb_i,
                                                   const float* __restrict__ g_i,
                                                   const float* __restrict__ b_i,
                                                   const float* __restrict__ m_i,
                                                   const float* __restrict__ v_i,
                                                   float* __restrict__ h,
                                                   __hip_bfloat16* __restrict__ hb) {
    const int wv = threadIdx.x >> 6, l = threadIdx.x & 63;
    const int n = blockIdx.x * 4 + wv;
    if (n >= NN || l >= 48) return;
    const int beg = rp[n], end = rp[n + 1];
    const int head = l >> 2;   // 0..11 (also the head of this lane's 32-col slice)
    const int j4 = l & 3;

    // 4-lane-parallel per-head max
    float mx = -INFINITY;
    for (int i = beg + j4; i < end; i += 4) mx = fmaxf(mx, logits[(size_t)i * HH + head]);
    mx = fmaxf(mx, __shfl_xor(mx, 1, 64));
    mx = fmaxf(mx, __shfl_xor(mx, 2, 64));
    // 4-lane-parallel per-head sum of exp
    float sum = 0.f;
    for (int i = beg + j4; i < end; i += 4) sum += __expf(logits[(size_t)i * HH + head] - mx);
    sum += __shfl_xor(sum, 1, 64);
    sum += __shfl_xor(sum, 2, 64);
    const float m_h = mx;
    const float inv_h = 1.f / (sum + 1e-16f);

    const int c0 = l * 8;
    float acc[8] = {};
    for (int i = beg; i < end; ++i) {
        const float a = __expf(logits[(size_t)i * HH + head] - m_h) * inv_h;
        const int s = src_p[i];
        const uint4 vx = *(const uint4*)(xlr + (size_t)s * 768 + c0);
        const u32* xw = (const u32*)&vx;
#pragma unroll
        for (int q = 0; q < 4; ++q) {
            acc[2 * q]     += bf2f((unsigned short)(xw[q] & 0xffff)) * a;
            acc[2 * q + 1] += bf2f((unsigned short)(xw[q] >> 16)) * a;
        }
    }
    const float4 cb0 = *(const float4*)(cb_i + c0), cb1 = *(const float4*)(cb_i + c0 + 4);
    const float4 gg0 = *(const float4*)(g_i + c0),  gg1 = *(const float4*)(g_i + c0 + 4);
    const float4 bb0 = *(const float4*)(b_i + c0),  bb1 = *(const float4*)(b_i + c0 + 4);
    const float4 mm0 = *(const float4*)(m_i + c0),  mm1 = *(const float4*)(m_i + c0 + 4);
    const float4 vv0 = *(const float4*)(v_i + c0),  vv1 = *(const float4*)(v_i + c0 + 4);
    const float cbv[8] = {cb0.x, cb0.y, cb0.z, cb0.w, cb1.x, cb1.y, cb1.z, cb1.w};
    const float gv[8]  = {gg0.x, gg0.y, gg0.z, gg0.w, gg1.x, gg1.y, gg1.z, gg1.w};
    const float bv[8]  = {bb0.x, bb0.y, bb0.z, bb0.w, bb1.x, bb1.y, bb1.z, bb1.w};
    const float mv[8]  = {mm0.x, mm0.y, mm0.z, mm0.w, mm1.x, mm1.y, mm1.z, mm1.w};
    const float vvv[8] = {vv0.x, vv0.y, vv0.z, vv0.w, vv1.x, vv1.y, vv1.z, vv1.w};
    float4 h0 = *(const float4*)(h + (size_t)n * DD + c0);
    float4 h1 = *(const float4*)(h + (size_t)n * DD + c0 + 4);
    float hv[8] = {h0.x, h0.y, h0.z, h0.w, h1.x, h1.y, h1.z, h1.w};
    unsigned int ow[4];
#pragma unroll
    for (int q = 0; q < 8; ++q) {
        float o = acc[q] + cbv[q];
        o = (o - mv[q]) * rsqrtf(vvv[q] + 1e-5f) * gv[q] + bv[q];
        hv[q] = siluf(o) + hv[q];
    }
#pragma unroll
    for (int q = 0; q < 4; ++q) {
        const unsigned short b0 = __bfloat16_as_ushort(__float2bfloat16(hv[2 * q]));
        const unsigned short b1 = __bfloat16_as_ushort(__float2bfloat16(hv[2 * q + 1]));
        ow[q] = (unsigned int)b0 | ((unsigned int)b1 << 16);
    }
    *(float4*)(h + (size_t)n * DD + c0) = make_float4(hv[0], hv[1], hv[2], hv[3]);
    *(float4*)(h + (size_t)n * DD + c0 + 4) = make_float4(hv[4], hv[5], hv[6], hv[7]);
    *(uint4*)(hb + (size_t)n * DD + c0) = *(uint4*)ow;
}

// ============ pooling: segmented (batch sorted) ============
__global__ void k_fill(float* __restrict__ p, float v, int n) {
    int i = blockIdx.x * blockDim.x + threadIdx.x;
    if (i < n) p[i] = v;
}

__global__ __launch_bounds__(384) void k_pool2(const float* __restrict__ h,
                                               const int* __restrict__ batch,
                                               float* __restrict__ gsum,
                                               float* __restrict__ gmax,
                                               float* __restrict__ gcnt) {
    const int j = threadIdx.x;
    const int n0 = blockIdx.x * 256;
    const int n1 = min(n0 + 256, NN);
    int cur = batch[n0];
    float s = 0.f, mx = -INFINITY;
    int cnt = 0;
    for (int n = n0; n < n1; ++n) {
        const int g = batch[n];
        if (g != cur) {
            atomicAdd(&gsum[cur * DD + j], s);
            atomicMaxF(&gmax[cur * DD + j], mx);
            if (j == 0) atomicAdd(&gcnt[cur], (float)cnt);
            s = 0.f; mx = -INFINITY; cnt = 0; cur = g;
        }
        const float v = h[(size_t)n * DD + j];
        s += v; mx = fmaxf(mx, v); ++cnt;
    }
    atomicAdd(&gsum[cur * DD + j], s);
    atomicMaxF(&gmax[cur * DD + j], mx);
    if (j == 0) atomicAdd(&gcnt[cur], (float)cnt);
}

// ============ per-graph MLP head (fp32 output) ============
__global__ __launch_bounds__(384) void k_head(const float* __restrict__ gsum,
                                              const float* __restrict__ gmax,
                                              const float* __restrict__ gcnt,
                                              const float* __restrict__ pW,
                                              const float* __restrict__ pb,
                                              const float* __restrict__ hW1,
                                              const float* __restrict__ hb1,
                                              const float* __restrict__ hW2,
                                              const float* __restrict__ hb2,
                                              const float* __restrict__ hW3,
                                              const float* __restrict__ hb3,
                                              float* __restrict__ out) {
    const int g = blockIdx.x, j = threadIdx.x;
    __shared__ float hg[2 * DD];
    __shared__ float p1[DD];
    __shared__ float p2[DD];
    __shared__ float p3[DD / 2];
    __shared__ float red[6];
    const float cnt = fmaxf(gcnt[g], 1.f);
    hg[j] = gsum[g * DD + j] / cnt;
    hg[DD + j] = gmax[g * DD + j];
    __syncthreads();
    float a = pb[j];
    for (int k = 0; k < 2 * DD; ++k) a += hg[k] * pW[(size_t)k * DD + j];
    p1[j] = siluf(a);
    __syncthreads();
    a = hb1[j];
    for (int k = 0; k < DD; ++k) a += p1[k] * hW1[(size_t)k * DD + j];
    p2[j] = siluf(a);
    __syncthreads();
    if (j < DD / 2) {
        a = hb2[j];
        for (int k = 0; k < DD; ++k) a += p2[k] * hW2[(size_t)k * (DD / 2) + j];
        p3[j] = siluf(a);
    }
    __syncthreads();
    float v = (j < DD / 2) ? p3[j] * hW3[j] : 0.f;
#pragma unroll
    for (int off = 32; off > 0; off >>= 1) v += __shfl_down(v, off, 64);
    if ((j & 63) == 0) red[j >> 6] = v;
    __syncthreads();
    if (j == 0) {
        float s = 0.f;
        for (int w = 0; w < 6; ++w) s += red[w];
        out[g] = s + hb3[0];
    }
}

static inline int gemm_grid(int M, int N) {
    const int nr = (M + 127) >> 7, nc = N >> 7;
    return ((nr + 7) >> 3) * nc * 8;
}

extern "C" void kernel_launch(void* const* d_in, const int* in_sizes, int n_in,
                              void* d_out, int out_size, void* d_ws, size_t ws_size,
                              hipStream_t stream) {
    (void)in_sizes; (void)n_in; (void)out_size; (void)ws_size;
    const float* x      = (const float*)d_in[0];
    const float* pos    = (const float*)d_in[1];
    const int*   ei     = (const int*)d_in[2];
    const int*   batch  = (const int*)d_in[3];
    const float* emb_W  = (const float*)d_in[4];
    const float* emb_b  = (const float*)d_in[5];
    const float* emb_g  = (const float*)d_in[6];
    const float* emb_be = (const float*)d_in[7];
    const float* eW1    = (const float*)d_in[8];
    const float* eb1    = (const float*)d_in[9];
    const float* eW2    = (const float*)d_in[10];
    const float* eb2    = (const float*)d_in[11];
    const float* e_g    = (const float*)d_in[12];
    const float* e_be   = (const float*)d_in[13];
    const float* Wl     = (const float*)d_in[14];
    const float* bl     = (const float*)d_in[15];
    const float* Wr     = (const float*)d_in[16];
    const float* br     = (const float*)d_in[17];
    const float* We     = (const float*)d_in[18];
    const float* att    = (const float*)d_in[19];
    const float* cb     = (const float*)d_in[20];
    const float* bn_g   = (const float*)d_in[21];
    const float* bn_b   = (const float*)d_in[22];
    const float* bn_m   = (const float*)d_in[23];
    const float* bn_v   = (const float*)d_in[24];
    const float* pW     = (const float*)d_in[25];
    const float* pb     = (const float*)d_in[26];
    const float* hW1    = (const float*)d_in[27];
    const float* hb1    = (const float*)d_in[28];
    const float* hW2    = (const float*)d_in[29];
    const float* hb2    = (const float*)d_in[30];
    const float* hW3    = (const float*)d_in[31];
    const float* hb3    = (const float*)d_in[32];

    char* wp = (char*)d_ws;
    auto carve = [&](size_t bytes) -> void* {
        void* p = (void*)wp;
        wp += (bytes + 255) & ~(size_t)255;
        return p;
    };
    float* h      = (float*)carve((size_t)NN * DD * 4);
    __hip_bfloat16* hbf = (__hip_bfloat16*)carve((size_t)NN * DD * 2);
    __hip_bfloat16* xlr = (__hip_bfloat16*)carve((size_t)NN * 768 * 2);
    __hip_bfloat16* ebf = (__hip_bfloat16*)carve((size_t)EE * DD * 2);
    float* logits = (float*)carve((size_t)EE * HH * 4);
    int* deg      = (int*)carve((size_t)NN * 4);
    int* cursor   = (int*)carve((size_t)NN * 4);
    int* rp       = (int*)carve((size_t)(NN + 1) * 4);
    int* col_e    = (int*)carve((size_t)EE * 4);
    int* src_p    = (int*)carve((size_t)EE * 4);
    int* dst_p    = (int*)carve((size_t)EE * 4);
    float* gsum   = (float*)carve((size_t)GG * DD * 4);
    float* gmax   = (float*)carve((size_t)GG * DD * 4);
    float* gcnt   = (float*)carve((size_t)GG * 4);
    __hip_bfloat16* Wlrt = (__hip_bfloat16*)carve((size_t)LL * 768 * DD * 2);
    __hip_bfloat16* Wet  = (__hip_bfloat16*)carve((size_t)LL * DD * DD * 2);
    float* blr    = (float*)carve((size_t)LL * 768 * 4);
    __hip_bfloat16* eW1t = (__hip_bfloat16*)carve((size_t)DD * 128 * 2);
    __hip_bfloat16* eW2t = (__hip_bfloat16*)carve((size_t)DD * DD * 2);

    __hip_bfloat16* rbfc = (__hip_bfloat16*)logits;  // CHUNK*128*2 = 8.39 MB <= 9.6 MB
    __hip_bfloat16* tc   = xlr;                      // CHUNK*384*2 = 25.2 MB <= 30.7 MB

    hipMemsetAsync(deg, 0, (size_t)NN * 4, stream);
    hipMemsetAsync(cursor, 0, (size_t)NN * 4, stream);

    // ---- weight prep ----
    {
        const int nblkLR = (int)(((size_t)LL * 768 * DD + 255) / 256);
        const int nblk6 = (int)(((size_t)LL * DD * DD + 255) / 256);
        k_twlr<<<nblkLR, 256, 0, stream>>>(Wl, Wr, Wlrt);
        k_tw<<<nblk6, 256, 0, stream>>>(We, Wet, LL);
        k_blr<<<(LL * 768 + 255) / 256, 256, 0, stream>>>(bl, br, blr);
        k_tw<<<(DD * DD + 255) / 256, 256, 0, stream>>>(eW2, eW2t, 1);
        k_tw1<<<(DD * 128 + 255) / 256, 256, 0, stream>>>(eW1, eW1t);
    }

    // ---- node embedding ----
    k_node_embed<<<NN, 384, 0, stream>>>(x, emb_W, emb_b, emb_g, emb_be, h, hbf);

    // ---- CSR + edge permutation ----
    k_deg<<<(EE + 255) / 256, 256, 0, stream>>>(ei, deg);
    k_scan<<<1, 1024, 0, stream>>>(deg, rp);
    k_scatter<<<(EE + 255) / 256, 256, 0, stream>>>(ei, rp, cursor, col_e);
    k_perm<<<(EE + 255) / 256, 256, 0, stream>>>(ei, col_e, src_p, dst_p);

    // ---- edge encoder (chunked, CSR order): rbf -> t -> ebf, then LN in-place ----
    for (int c0 = 0; c0 < EE; c0 += CHUNK) {
        const int cm = (EE - c0 < CHUNK) ? (EE - c0) : CHUNK;
        k_rbf_chunk<<<(cm + 1) / 2, 256, 0, stream>>>(pos, src_p, dst_p, c0, cm, rbfc);
        k_gemm_bt<true, true><<<gemm_grid(cm, DD), 256, 0, stream>>>(rbfc, eW1t, eb1, tc, cm, DD, 128);
        k_gemm_bt<true, false><<<gemm_grid(cm, DD), 256, 0, stream>>>(tc, eW2t, eb2,
                                                                      ebf + (size_t)c0 * DD, cm, DD, DD);
    }
    k_ln_rows<<<EE / 8, 512, 0, stream>>>(ebf, e_g, e_be);

    // ---- layers ----
    for (int i = 0; i < LL; ++i) {
        const __hip_bfloat16* Wlrt_i = Wlrt + (size_t)i * 768 * DD;
        const __hip_bfloat16* Wet_i  = Wet + (size_t)i * DD * DD;
        const float* blr_i = blr + (size_t)i * 768;
        const float* att_i = att + (size_t)i * HH * CC;
        const float* cb_i  = cb + (size_t)i * DD;
        const float* bng_i = bn_g + (size_t)i * DD;
        const float* bnb_i = bn_b + (size_t)i * DD;
        const float* bnm_i = bn_m + (size_t)i * DD;
        const float* bnv_i = bn_v + (size_t)i * DD;

        k_gemm_bt<true, false><<<gemm_grid(NN, 768), 256, 0, stream>>>(hbf, Wlrt_i, blr_i, xlr,
                                                                       NN, 768, DD);
        k_gemm_attn<<<gemm_grid(EE, DD), 256, 0, stream>>>(ebf, Wet_i, xlr, src_p, dst_p,
                                                           att_i, logits, EE, DD);
        k_node_aggr<<<(NN + 3) / 4, 256, 0, stream>>>(logits, xlr, src_p, rp, cb_i, bng_i, bnb_i,
                                                      bnm_i, bnv_i, h, hbf);
    }

    // ---- pooling + head ----
    hipMemsetAsync(gsum, 0, (size_t)GG * DD * 4, stream);
    hipMemsetAsync(gcnt, 0, (size_t)GG * 4, stream);
    k_fill<<<(GG * DD + 255) / 256, 256, 0, stream>>>(gmax, -INFINITY, GG * DD);
    k_pool2<<<(NN + 255) / 256, 384, 0, stream>>>(h, batch, gsum, gmax, gcnt);
    k_head<<<GG, 384, 0, stream>>>(gsum, gmax, gcnt, pW, pb, hW1, hb1, hW2, hb2, hW3, hb3,
                                   (float*)d_out);
}

// Round 12
// 1775.035 us; speedup vs baseline: 1.0686x; 1.0378x over previous
//
#include <hip/hip_runtime.h>
#include <hip/hip_bf16.h>
#include <math.h>

#define NN 20000
#define EE 200000
#define GG 32
#define DD 384
#define HH 12
#define CC 32
#define LL 6
#define NRBF 100
#define CHUNK 40000

typedef short s16x8 __attribute__((ext_vector_type(8)));
typedef float f32x4 __attribute__((ext_vector_type(4)));
typedef unsigned int u32;

__device__ __forceinline__ float siluf(float x) { return x / (1.f + __expf(-x)); }
__device__ __forceinline__ float bf2f(unsigned short u) {
    return __uint_as_float(((unsigned int)u) << 16);
}

__device__ __forceinline__ void atomicMaxF(float* addr, float val) {
    if (val >= 0.f) atomicMax((int*)addr, __float_as_int(val));
    else atomicMin((unsigned int*)addr, __float_as_uint(val));
}

// async global->LDS, 16B per lane; LDS dest = wave-uniform base + lane*16
__device__ __forceinline__ void gload16(const void* g, void* l) {
    __builtin_amdgcn_global_load_lds((const __attribute__((address_space(1))) u32*)g,
                                     (__attribute__((address_space(3))) u32*)l, 16, 0, 0);
}

// XCD-aware tile decode: col-tiles of one row-tile run consecutively on ONE XCD
// (dispatch round-robins XCDs by linear workgroup id) -> A row-tile stays L2-hot,
// A read from HBM exactly once (verified round 7: FETCH 301->156 MB).
__device__ __forceinline__ bool tile_decode(int NC, int nrows, int& rowt, int& col) {
    const int t = blockIdx.x;
    const int q = t >> 3;
    col = q % NC;
    rowt = (q / NC) * 8 + (t & 7);
    return rowt < nrows;
}

// Symbol the harness template named; defined for safety, never launched.
__global__ void EquivariantProteinGNN_45552423141948_kernel() {}

// ---- shared BK=32 K-loop (128x128 tile, 4 waves, 16KB As + 16KB Bs).
// BK=64 tried in round 9: occupancy 31%->21%, net regression -> reverted (m132 analog).
// LDS row = 64B = 4 chunks of 16B, chunk-swizzled c ^= (row>>1)&3 via pre-swizzled
// global SOURCE + swizzled READ (same involution both sides; linear gload_lds dest).
__device__ __forceinline__ void gemm_kloop(const __hip_bfloat16* __restrict__ A,
                                           const __hip_bfloat16* __restrict__ Bt,
                                           int M, int K, int m0, int n0,
                                           unsigned short* As, unsigned short* Bs,
                                           f32x4 (&acc)[4][4]) {
    char* AsB = (char*)As;
    char* BsB = (char*)Bs;
    const int t = threadIdx.x;
    const int w = t >> 6, l = t & 63;
    const int wr = w >> 1, wc = w & 1;

    const int seg0 = 2 * w, seg1 = seg0 + 1;
    const int r0s = seg0 * 16 + (l >> 2);
    const int r1s = seg1 * 16 + (l >> 2);
    const int cg0 = (l & 3) ^ ((r0s >> 1) & 3);
    const int cg1 = (l & 3) ^ ((r1s >> 1) & 3);
    const size_t aSrc0 = (size_t)min(m0 + r0s, M - 1) * K + cg0 * 8;
    const size_t aSrc1 = (size_t)min(m0 + r1s, M - 1) * K + cg1 * 8;
    const size_t bSrc0 = (size_t)(n0 + r0s) * K + cg0 * 8;
    const size_t bSrc1 = (size_t)(n0 + r1s) * K + cg1 * 8;
    unsigned short* AsW0 = As + seg0 * 512;
    unsigned short* AsW1 = As + seg1 * 512;
    unsigned short* BsW0 = Bs + seg0 * 512;
    unsigned short* BsW1 = Bs + seg1 * 512;

    int aoff[4], boff[4];
#pragma unroll
    for (int m = 0; m < 4; ++m) {
        const int row = wr * 64 + m * 16 + (l & 15);
        aoff[m] = row * 64 + ((((l >> 4)) ^ ((row >> 1) & 3)) << 4);
        const int rowb = wc * 64 + m * 16 + (l & 15);
        boff[m] = rowb * 64 + ((((l >> 4)) ^ ((rowb >> 1) & 3)) << 4);
    }

    for (int kk = 0; kk < K; kk += 32) {
        __syncthreads();
        gload16(A + aSrc0 + kk, AsW0);
        gload16(A + aSrc1 + kk, AsW1);
        gload16(Bt + bSrc0 + kk, BsW0);
        gload16(Bt + bSrc1 + kk, BsW1);
        __syncthreads();
        s16x8 af[4], bfr[4];
#pragma unroll
        for (int m = 0; m < 4; ++m) af[m] = *(const s16x8*)(AsB + aoff[m]);
#pragma unroll
        for (int n = 0; n < 4; ++n) bfr[n] = *(const s16x8*)(BsB + boff[n]);
#pragma unroll
        for (int m = 0; m < 4; ++m)
#pragma unroll
            for (int n = 0; n < 4; ++n)
                acc[m][n] = __builtin_amdgcn_mfma_f32_16x16x32_bf16(af[m], bfr[n], acc[m][n], 0, 0, 0);
    }
}

// ============ bf16 MFMA GEMM: C[M][N] = A[M][K] @ Bt[N][K]^T (+bias)(+silu) -> bf16 ============
template<bool BIAS, bool SILU>
__global__ __launch_bounds__(256) void k_gemm_bt(const __hip_bfloat16* __restrict__ A,
                                                 const __hip_bfloat16* __restrict__ Bt,
                                                 const float* __restrict__ bias,
                                                 __hip_bfloat16* __restrict__ Cmat,
                                                 int M, int N, int K) {
    int rowt, colt;
    if (!tile_decode(N >> 7, (M + 127) >> 7, rowt, colt)) return;
    const int m0 = rowt << 7, n0 = colt << 7;

    __shared__ unsigned short As[128 * 32];
    __shared__ unsigned short Bs[128 * 32];
    const int l = threadIdx.x & 63;
    const int w = threadIdx.x >> 6;
    const int wr = w >> 1, wc = w & 1;

    f32x4 acc[4][4] = {};
    gemm_kloop(A, Bt, M, K, m0, n0, As, Bs, acc);

#pragma unroll
    for (int n = 0; n < 4; ++n) {
        const int col = n0 + wc * 64 + n * 16 + (l & 15);
        const float bv = BIAS ? bias[col] : 0.f;
#pragma unroll
        for (int m = 0; m < 4; ++m) {
            const int rbase = m0 + wr * 64 + m * 16 + ((l >> 4) << 2);
#pragma unroll
            for (int r = 0; r < 4; ++r) {
                const int row = rbase + r;
                if (row < M) {
                    float v = acc[m][n][r] + bv;
                    if (SILU) v = siluf(v);
                    Cmat[(size_t)row * N + col] = __float2bfloat16(v);
                }
            }
        }
    }
}

// ===== encoder GEMM1 with A = RBF features computed in-register (no rbf kernel/buffer) =====
// A-tile staged via ds_write_b128, lane-linear (byte t*16 and 4096+t*16): conflict-free.
// LDS slot sc holds global chunk sc ^ ((row>>1)&3) -- same involution the reads expect.
// Same fp32 formula + RNE bf16 rounding as the old k_rbf_chunk -> bit-identical A.
__global__ __launch_bounds__(256) void k_gemm_rbf(const float* __restrict__ pos,
                                                  const int* __restrict__ src_p,
                                                  const int* __restrict__ dst_p,
                                                  int e0, int cm,
                                                  const __hip_bfloat16* __restrict__ Bt,
                                                  const float* __restrict__ bias,
                                                  __hip_bfloat16* __restrict__ Cmat) {
    int rowt, colt;
    if (!tile_decode(DD >> 7, (cm + 127) >> 7, rowt, colt)) return;
    const int m0 = rowt << 7, n0 = colt << 7;

    __shared__ unsigned short As[128 * 32];
    __shared__ unsigned short Bs[128 * 32];
    char* AsB = (char*)As;
    char* BsB = (char*)Bs;
    const int t = threadIdx.x;
    const int w = t >> 6, l = t & 63;
    const int wr = w >> 1, wc = w & 1;

    const float spacing = 30.f / 99.f;
    const float gamma = 1.f / (spacing * spacing + 1e-8f);

    // A staging: thread t owns rows rA0 = t>>2 and rA1 = 64 + t>>2, slot sc = t&3.
    const int rA0 = t >> 2, rA1 = 64 + (t >> 2);
    const int sc = t & 3;
    const int cgA0 = sc ^ ((rA0 >> 1) & 3);
    const int cgA1 = sc ^ ((rA1 >> 1) & 3);
    float distA[2];
#pragma unroll
    for (int i = 0; i < 2; ++i) {
        const int row = i ? rA1 : rA0;
        const int e = e0 + min(m0 + row, cm - 1);
        const int sN = src_p[e], dN = dst_p[e];
        const float dx = pos[sN * 3 + 0] - pos[dN * 3 + 0];
        const float dy = pos[sN * 3 + 1] - pos[dN * 3 + 1];
        const float dz = pos[sN * 3 + 2] - pos[dN * 3 + 2];
        distA[i] = sqrtf(dx * dx + dy * dy + dz * dz);
    }

    // B staging: original gload segment mapping (K = 128)
    const int seg0 = 2 * w, seg1 = seg0 + 1;
    const int r0s = seg0 * 16 + (l >> 2);
    const int r1s = seg1 * 16 + (l >> 2);
    const int cgB0 = (l & 3) ^ ((r0s >> 1) & 3);
    const int cgB1 = (l & 3) ^ ((r1s >> 1) & 3);
    const size_t bSrc0 = (size_t)(n0 + r0s) * 128 + cgB0 * 8;
    const size_t bSrc1 = (size_t)(n0 + r1s) * 128 + cgB1 * 8;
    unsigned short* BsW0 = Bs + seg0 * 512;
    unsigned short* BsW1 = Bs + seg1 * 512;

    int aoff[4], boff[4];
#pragma unroll
    for (int m = 0; m < 4; ++m) {
        const int row = wr * 64 + m * 16 + (l & 15);
        aoff[m] = row * 64 + ((((l >> 4)) ^ ((row >> 1) & 3)) << 4);
        const int rowb = wc * 64 + m * 16 + (l & 15);
        boff[m] = rowb * 64 + ((((l >> 4)) ^ ((rowb >> 1) & 3)) << 4);
    }

    f32x4 acc[4][4] = {};

    for (int kk = 0; kk < 128; kk += 32) {
        __syncthreads();
        gload16(Bt + bSrc0 + kk, BsW0);
        gload16(Bt + bSrc1 + kk, BsW1);
        // compute + pack the two 8-value RBF chunks this thread stages
        uint4 pk[2];
#pragma unroll
        for (int i = 0; i < 2; ++i) {
            const int kb = kk + (i ? cgA1 : cgA0) * 8;
            const float dist = distA[i];
            u32 w4[4];
#pragma unroll
            for (int j = 0; j < 4; ++j) {
                const int k0 = kb + 2 * j, k1 = k0 + 1;
                const float d0 = dist - (float)k0 * spacing;
                const float d1 = dist - (float)k1 * spacing;
                const float f0 = (k0 < NRBF) ? __expf(-gamma * d0 * d0) : 0.f;
                const float f1 = (k1 < NRBF) ? __expf(-gamma * d1 * d1) : 0.f;
                w4[j] = (u32)__bfloat16_as_ushort(__float2bfloat16(f0)) |
                        ((u32)__bfloat16_as_ushort(__float2bfloat16(f1)) << 16);
            }
            pk[i] = make_uint4(w4[0], w4[1], w4[2], w4[3]);
        }
        *(uint4*)(AsB + t * 16) = pk[0];          // row rA0, slot sc
        *(uint4*)(AsB + 4096 + t * 16) = pk[1];   // row rA1, slot sc
        __syncthreads();
        s16x8 af[4], bfr[4];
#pragma unroll
        for (int m = 0; m < 4; ++m) af[m] = *(const s16x8*)(AsB + aoff[m]);
#pragma unroll
        for (int n = 0; n < 4; ++n) bfr[n] = *(const s16x8*)(BsB + boff[n]);
#pragma unroll
        for (int m = 0; m < 4; ++m)
#pragma unroll
            for (int n = 0; n < 4; ++n)
                acc[m][n] = __builtin_amdgcn_mfma_f32_16x16x32_bf16(af[m], bfr[n], acc[m][n], 0, 0, 0);
    }

    // epilogue: bias + silu -> tc
#pragma unroll
    for (int n = 0; n < 4; ++n) {
        const int col = n0 + wc * 64 + n * 16 + (l & 15);
        const float bv = bias[col];
#pragma unroll
        for (int m = 0; m < 4; ++m) {
            const int rbase = m0 + wr * 64 + m * 16 + ((l >> 4) << 2);
#pragma unroll
            for (int r = 0; r < 4; ++r) {
                const int row = rbase + r;
                if (row < cm) {
                    Cmat[(size_t)row * DD + col] = __float2bfloat16(siluf(acc[m][n][r] + bv));
                }
            }
        }
    }
}

// ===== fused: ee = ebf @ Wet^T, then logits[p][h] over CSR-ordered edges =====
// Epilogue via per-wave LDS transpose (aliases As/Bs). Swizzle col^(row<<2):
// verified 0 bank conflicts in round-9/10 counters. Gathers issued BEFORE the LDS
// scatter so their latency hides under the ds_write/ds_read work.
__global__ __launch_bounds__(256) void k_gemm_attn(const __hip_bfloat16* __restrict__ A,
                                                   const __hip_bfloat16* __restrict__ Bt,
                                                   const __hip_bfloat16* __restrict__ xlr,
                                                   const int* __restrict__ src_p,
                                                   const int* __restrict__ dst_p,
                                                   const float* __restrict__ att_i,
                                                   float* __restrict__ logits,
                                                   int M, int K) {
    int rowt, colt;
    if (!tile_decode(DD >> 7, (M + 127) >> 7, rowt, colt)) return;
    const int m0 = rowt << 7, n0 = colt << 7;

    __shared__ char smem[16384];
    unsigned short* As = (unsigned short*)smem;
    unsigned short* Bs = (unsigned short*)(smem + 8192);
    const int l = threadIdx.x & 63;
    const int w = threadIdx.x >> 6;
    const int wr = w >> 1, wc = w & 1;

    f32x4 acc[4][4] = {};
    gemm_kloop(A, Bt, M, K, m0, n0, As, Bs, acc);

    __syncthreads();  // all waves done with As/Bs; reuse as per-wave epilogue scratch

    // ---- LDS-transpose epilogue ----
    float* ep = (float*)(smem + w * 4096);  // per-wave 16x64 f32
    const int row_l = l >> 2;               // 0..15: local edge row this lane reduces
    const int c0 = (l & 3) << 4;            // 16-col slice within the 64-col window
    const int gcol = n0 + wc * 64 + c0;
    const int hbase = (n0 + wc * 64) >> 5;  // first of 2 heads in this wave's window
    const int rswz = row_l << 2;

    float attv[16];
#pragma unroll
    for (int k = 0; k < 4; ++k)
        *(float4*)(attv + 4 * k) = *(const float4*)(att_i + gcol + 4 * k);

#pragma unroll
    for (int m = 0; m < 4; ++m) {
        // issue independent gathers FIRST (latency hides under the LDS transpose)
        const int growu = m0 + wr * 64 + m * 16 + row_l;
        const int grow = min(growu, M - 1);
        const int s = src_p[grow], d = dst_p[grow];
        const uint4 vl0 = *(const uint4*)(xlr + (size_t)s * 768 + gcol);
        const uint4 vl1 = *(const uint4*)(xlr + (size_t)s * 768 + gcol + 8);
        const uint4 vr0 = *(const uint4*)(xlr + (size_t)d * 768 + 384 + gcol);
        const uint4 vr1 = *(const uint4*)(xlr + (size_t)d * 768 + 384 + gcol + 8);

        // scatter this wave's 16x64 acc window into LDS (col ^ row<<2: conflict-free)
#pragma unroll
        for (int n = 0; n < 4; ++n)
#pragma unroll
            for (int r = 0; r < 4; ++r) {
                const int row = ((l >> 4) << 2) + r;
                const int col = (n << 4) + (l & 15);
                ep[(row << 6) + (col ^ (row << 2))] = acc[m][n][r];
            }
        // transposed read: lane owns one row, 16 contiguous cols (4x f32x4)
        float av[16];
#pragma unroll
        for (int k = 0; k < 4; ++k) {
            const int sc0 = (c0 + (k << 2)) ^ rswz;
            *(f32x4*)(av + 4 * k) = *(const f32x4*)(ep + (row_l << 6) + sc0);
        }
        const u32 lw[8] = {vl0.x, vl0.y, vl0.z, vl0.w, vl1.x, vl1.y, vl1.z, vl1.w};
        const u32 rw[8] = {vr0.x, vr0.y, vr0.z, vr0.w, vr1.x, vr1.y, vr1.z, vr1.w};
        float part = 0.f;
#pragma unroll
        for (int q = 0; q < 8; ++q) {
            float v0 = av[2 * q] + bf2f((unsigned short)(lw[q] & 0xffff)) +
                       bf2f((unsigned short)(rw[q] & 0xffff));
            float v1 = av[2 * q + 1] + bf2f((unsigned short)(lw[q] >> 16)) +
                       bf2f((unsigned short)(rw[q] >> 16));
            v0 = (v0 > 0.f) ? v0 : 0.2f * v0;
            v1 = (v1 > 0.f) ? v1 : 0.2f * v1;
            part += v0 * attv[2 * q] + v1 * attv[2 * q + 1];
        }
        part += __shfl_xor(part, 1, 64);  // combine the 2 half-head lanes
        if (growu < M && (l & 1) == 0)
            logits[(size_t)growu * HH + hbase + ((l & 2) >> 1)] = part;
    }
}

// ============ weight prep ============
__global__ void k_tw(const float* __restrict__ in, __hip_bfloat16* __restrict__ out, int nmat) {
    const size_t idx = (size_t)blockIdx.x * 256 + threadIdx.x;
    if (idx >= (size_t)nmat * DD * DD) return;
    const int m = idx / (DD * DD);
    const int rem = idx - (size_t)m * DD * DD;
    const int n = rem / DD, k = rem - n * DD;
    out[idx] = __float2bfloat16(in[(size_t)m * DD * DD + (size_t)k * DD + n]);
}

// fused Wl|Wr -> bf16 [L][768(n)][384(k)] transposed
__global__ void k_twlr(const float* __restrict__ Wl, const float* __restrict__ Wr,
                       __hip_bfloat16* __restrict__ out) {
    const size_t idx = (size_t)blockIdx.x * 256 + threadIdx.x;
    if (idx >= (size_t)LL * 768 * DD) return;
    const int i = idx / (768 * DD);
    const int rem = idx - (size_t)i * 768 * DD;
    const int n = rem / DD, k = rem - n * DD;
    const float v = (n < DD) ? Wl[(size_t)i * DD * DD + (size_t)k * DD + n]
                             : Wr[(size_t)i * DD * DD + (size_t)k * DD + (n - DD)];
    out[idx] = __float2bfloat16(v);
}

__global__ void k_blr(const float* __restrict__ bl, const float* __restrict__ br,
                      float* __restrict__ blr) {
    const int idx = blockIdx.x * 256 + threadIdx.x;
    if (idx >= LL * 768) return;
    const int i = idx / 768, c = idx - i * 768;
    blr[idx] = (c < DD) ? bl[i * DD + c] : br[i * DD + c - DD];
}

// eW1 f32 [100][384] -> bf16 [384][128] transposed, k>=100 zero-padded
__global__ void k_tw1(const float* __restrict__ in, __hip_bfloat16* __restrict__ out) {
    const int idx = blockIdx.x * 256 + threadIdx.x;
    if (idx >= DD * 128) return;
    const int n = idx >> 7, k = idx & 127;
    out[idx] = __float2bfloat16(k < NRBF ? in[(size_t)k * DD + n] : 0.f);
}

// ============ in-place row LayerNorm on bf16 [rows][384]; one wave per row ============
__global__ __launch_bounds__(512) void k_ln_rows(__hip_bfloat16* __restrict__ u,
                                                 const float* __restrict__ g,
                                                 const float* __restrict__ be) {
    const int w = threadIdx.x >> 6, l = threadIdx.x & 63;
    const int row = blockIdx.x * 8 + w;
    float vals[8];
    float s = 0.f, q = 0.f;
    if (l < 48) {
        const uint4 vu = *(const uint4*)(u + (size_t)row * DD + 8 * l);
        const unsigned int* uw = (const unsigned int*)&vu;
#pragma unroll
        for (int i = 0; i < 4; ++i) {
            vals[2 * i] = bf2f((unsigned short)(uw[i] & 0xffff));
            vals[2 * i + 1] = bf2f((unsigned short)(uw[i] >> 16));
        }
#pragma unroll
        for (int i = 0; i < 8; ++i) { s += vals[i]; q += vals[i] * vals[i]; }
    }
#pragma unroll
    for (int off = 1; off < 64; off <<= 1) {
        s += __shfl_xor(s, off, 64);
        q += __shfl_xor(q, off, 64);
    }
    const float mu = s / DD;
    const float rs = rsqrtf(q / DD - mu * mu + 1e-5f);
    if (l < 48) {
        unsigned int ow[4];
        const float4 g0 = *(const float4*)(g + 8 * l);
        const float4 g1 = *(const float4*)(g + 8 * l + 4);
        const float4 b0 = *(const float4*)(be + 8 * l);
        const float4 b1 = *(const float4*)(be + 8 * l + 4);
        const float gv[8] = {g0.x, g0.y, g0.z, g0.w, g1.x, g1.y, g1.z, g1.w};
        const float bv[8] = {b0.x, b0.y, b0.z, b0.w, b1.x, b1.y, b1.z, b1.w};
#pragma unroll
        for (int i = 0; i < 4; ++i) {
            const float y0 = (vals[2 * i] - mu) * rs * gv[2 * i] + bv[2 * i];
            const float y1 = (vals[2 * i + 1] - mu) * rs * gv[2 * i + 1] + bv[2 * i + 1];
            const unsigned short h0 = __bfloat16_as_ushort(__float2bfloat16(y0));
            const unsigned short h1 = __bfloat16_as_ushort(__float2bfloat16(y1));
            ow[i] = (unsigned int)h0 | ((unsigned int)h1 << 16);
        }
        *(uint4*)(u + (size_t)row * DD + 8 * l) = *(uint4*)ow;
    }
}

// ============ node embedding ============
__global__ __launch_bounds__(384) void k_node_embed(const float* __restrict__ x,
                                                    const float* __restrict__ W,
                                                    const float* __restrict__ b,
                                                    const float* __restrict__ g,
                                                    const float* __restrict__ be,
                                                    float* __restrict__ h,
                                                    __hip_bfloat16* __restrict__ hb) {
    const int n = blockIdx.x, j = threadIdx.x;
    __shared__ float xrow[20];
    __shared__ float red[12];
    if (j < 20) xrow[j] = x[n * 20 + j];
    __syncthreads();
    float acc = b[j];
#pragma unroll
    for (int k = 0; k < 20; ++k) acc += xrow[k] * W[k * DD + j];
    float s = acc, q = acc * acc;
#pragma unroll
    for (int off = 32; off > 0; off >>= 1) {
        s += __shfl_down(s, off, 64);
        q += __shfl_down(q, off, 64);
    }
    const int wid = j >> 6;
    if ((j & 63) == 0) { red[wid] = s; red[6 + wid] = q; }
    __syncthreads();
    if (j == 0) {
        float ts = 0.f, tq = 0.f;
        for (int w = 0; w < 6; ++w) { ts += red[w]; tq += red[6 + w]; }
        float mu = ts / DD;
        red[0] = mu; red[6] = tq / DD - mu * mu;
    }
    __syncthreads();
    const float mu = red[0], var = red[6];
    float y = (acc - mu) * rsqrtf(var + 1e-5f) * g[j] + be[j];
    y = siluf(y);
    h[(size_t)n * DD + j] = y;
    hb[(size_t)n * DD + j] = __float2bfloat16(y);
}

// ============ CSR build over dst ============
__global__ void k_deg(const int* __restrict__ ei, int* __restrict__ deg) {
    int e = blockIdx.x * blockDim.x + threadIdx.x;
    if (e < EE) atomicAdd(&deg[ei[EE + e]], 1);
}

__global__ __launch_bounds__(1024) void k_scan(const int* __restrict__ deg, int* __restrict__ rp) {
    __shared__ int buf[1024];
    __shared__ int carry_s;
    const int tid = threadIdx.x;
    if (tid == 0) carry_s = 0;
    __syncthreads();
    for (int base = 0; base < NN; base += 1024) {
        int v = (base + tid < NN) ? deg[base + tid] : 0;
        buf[tid] = v;
        __syncthreads();
        for (int off = 1; off < 1024; off <<= 1) {
            int t = (tid >= off) ? buf[tid - off] : 0;
            __syncthreads();
            buf[tid] += t;
            __syncthreads();
        }
        const int incl = buf[tid];
        const int carry = carry_s;
        if (base + tid < NN) rp[base + tid] = carry + incl - v;
        __syncthreads();
        if (tid == 1023) carry_s = carry + incl;
        __syncthreads();
    }
    if (tid == 0) rp[NN] = carry_s;
}

__global__ void k_scatter(const int* __restrict__ ei, const int* __restrict__ rp,
                          int* __restrict__ cursor, int* __restrict__ col_e) {
    int e = blockIdx.x * blockDim.x + threadIdx.x;
    if (e < EE) {
        int d = ei[EE + e];
        int p = atomicAdd(&cursor[d], 1);
        col_e[rp[d] + p] = e;
    }
}

// p -> original edge col_e[p]; materialize permuted src/dst
__global__ void k_perm(const int* __restrict__ ei, const int* __restrict__ col_e,
                       int* __restrict__ src_p, int* __restrict__ dst_p) {
    int p = blockIdx.x * blockDim.x + threadIdx.x;
    if (p < EE) {
        const int e = col_e[p];
        src_p[p] = ei[e];
        dst_p[p] = ei[EE + e];
    }
}

// ============ per-node softmax + aggregate + BN + silu + residual ============
// Stats phase wave-parallelized: 4 lanes per head stride the edge list, then a
// 2-step shfl_xor reduce within each aligned 4-lane group (round-11, +55 us).
__global__ __launch_bounds__(256) void k_node_aggr(const float* __restrict__ logits,
                                                   const __hip_bfloat16* __restrict__ xlr,
                                                   const int* __restrict__ src_p,
                                                   const int* __restrict__ rp,
                                                   const float* __restrict__ cb_i,
                                                   const float* __restrict__ g_i,
                                                   const float* __restrict__ b_i,
                                                   const float* __restrict__ m_i,
                                                   const float* __restrict__ v_i,
                                                   float* __restrict__ h,
                                                   __hip_bfloat16* __restrict__ hb) {
    const int wv = threadIdx.x >> 6, l = threadIdx.x & 63;
    const int n = blockIdx.x * 4 + wv;
    if (n >= NN || l >= 48) return;
    const int beg = rp[n], end = rp[n + 1];
    const int head = l >> 2;
    const int j4 = l & 3;

    float mx = -INFINITY;
    for (int i = beg + j4; i < end; i += 4) mx = fmaxf(mx, logits[(size_t)i * HH + head]);
    mx = fmaxf(mx, __shfl_xor(mx, 1, 64));
    mx = fmaxf(mx, __shfl_xor(mx, 2, 64));
    float sum = 0.f;
    for (int i = beg + j4; i < end; i += 4) sum += __expf(logits[(size_t)i * HH + head] - mx);
    sum += __shfl_xor(sum, 1, 64);
    sum += __shfl_xor(sum, 2, 64);
    const float m_h = mx;
    const float inv_h = 1.f / (sum + 1e-16f);

    const int c0 = l * 8;
    float acc[8] = {};
    for (int i = beg; i < end; ++i) {
        const float a = __expf(logits[(size_t)i * HH + head] - m_h) * inv_h;
        const int s = src_p[i];
        const uint4 vx = *(const uint4*)(xlr + (size_t)s * 768 + c0);
        const u32* xw = (const u32*)&vx;
#pragma unroll
        for (int q = 0; q < 4; ++q) {
            acc[2 * q]     += bf2f((unsigned short)(xw[q] & 0xffff)) * a;
            acc[2 * q + 1] += bf2f((unsigned short)(xw[q] >> 16)) * a;
        }
    }
    const float4 cb0 = *(const float4*)(cb_i + c0), cb1 = *(const float4*)(cb_i + c0 + 4);
    const float4 gg0 = *(const float4*)(g_i + c0),  gg1 = *(const float4*)(g_i + c0 + 4);
    const float4 bb0 = *(const float4*)(b_i + c0),  bb1 = *(const float4*)(b_i + c0 + 4);
    const float4 mm0 = *(const float4*)(m_i + c0),  mm1 = *(const float4*)(m_i + c0 + 4);
    const float4 vv0 = *(const float4*)(v_i + c0),  vv1 = *(const float4*)(v_i + c0 + 4);
    const float cbv[8] = {cb0.x, cb0.y, cb0.z, cb0.w, cb1.x, cb1.y, cb1.z, cb1.w};
    const float gv[8]  = {gg0.x, gg0.y, gg0.z, gg0.w, gg1.x, gg1.y, gg1.z, gg1.w};
    const float bv[8]  = {bb0.x, bb0.y, bb0.z, bb0.w, bb1.x, bb1.y, bb1.z, bb1.w};
    const float mv[8]  = {mm0.x, mm0.y, mm0.z, mm0.w, mm1.x, mm1.y, mm1.z, mm1.w};
    const float vvv[8] = {vv0.x, vv0.y, vv0.z, vv0.w, vv1.x, vv1.y, vv1.z, vv1.w};
    float4 h0 = *(const float4*)(h + (size_t)n * DD + c0);
    float4 h1 = *(const float4*)(h + (size_t)n * DD + c0 + 4);
    float hv[8] = {h0.x, h0.y, h0.z, h0.w, h1.x, h1.y, h1.z, h1.w};
    unsigned int ow[4];
#pragma unroll
    for (int q = 0; q < 8; ++q) {
        float o = acc[q] + cbv[q];
        o = (o - mv[q]) * rsqrtf(vvv[q] + 1e-5f) * gv[q] + bv[q];
        hv[q] = siluf(o) + hv[q];
    }
#pragma unroll
    for (int q = 0; q < 4; ++q) {
        const unsigned short b0 = __bfloat16_as_ushort(__float2bfloat16(hv[2 * q]));
        const unsigned short b1 = __bfloat16_as_ushort(__float2bfloat16(hv[2 * q + 1]));
        ow[q] = (unsigned int)b0 | ((unsigned int)b1 << 16);
    }
    *(float4*)(h + (size_t)n * DD + c0) = make_float4(hv[0], hv[1], hv[2], hv[3]);
    *(float4*)(h + (size_t)n * DD + c0 + 4) = make_float4(hv[4], hv[5], hv[6], hv[7]);
    *(uint4*)(hb + (size_t)n * DD + c0) = *(uint4*)ow;
}

// ============ pooling: segmented (batch sorted) ============
__global__ void k_fill(float* __restrict__ p, float v, int n) {
    int i = blockIdx.x * blockDim.x + threadIdx.x;
    if (i < n) p[i] = v;
}

__global__ __launch_bounds__(384) void k_pool2(const float* __restrict__ h,
                                               const int* __restrict__ batch,
                                               float* __restrict__ gsum,
                                               float* __restrict__ gmax,
                                               float* __restrict__ gcnt) {
    const int j = threadIdx.x;
    const int n0 = blockIdx.x * 256;
    const int n1 = min(n0 + 256, NN);
    int cur = batch[n0];
    float s = 0.f, mx = -INFINITY;
    int cnt = 0;
    for (int n = n0; n < n1; ++n) {
        const int g = batch[n];
        if (g != cur) {
            atomicAdd(&gsum[cur * DD + j], s);
            atomicMaxF(&gmax[cur * DD + j], mx);
            if (j == 0) atomicAdd(&gcnt[cur], (float)cnt);
            s = 0.f; mx = -INFINITY; cnt = 0; cur = g;
        }
        const float v = h[(size_t)n * DD + j];
        s += v; mx = fmaxf(mx, v); ++cnt;
    }
    atomicAdd(&gsum[cur * DD + j], s);
    atomicMaxF(&gmax[cur * DD + j], mx);
    if (j == 0) atomicAdd(&gcnt[cur], (float)cnt);
}

// ============ per-graph MLP head (fp32 output) ============
__global__ __launch_bounds__(384) void k_head(const float* __restrict__ gsum,
                                              const float* __restrict__ gmax,
                                              const float* __restrict__ gcnt,
                                              const float* __restrict__ pW,
                                              const float* __restrict__ pb,
                                              const float* __restrict__ hW1,
                                              const float* __restrict__ hb1,
                                              const float* __restrict__ hW2,
                                              const float* __restrict__ hb2,
                                              const float* __restrict__ hW3,
                                              const float* __restrict__ hb3,
                                              float* __restrict__ out) {
    const int g = blockIdx.x, j = threadIdx.x;
    __shared__ float hg[2 * DD];
    __shared__ float p1[DD];
    __shared__ float p2[DD];
    __shared__ float p3[DD / 2];
    __shared__ float red[6];
    const float cnt = fmaxf(gcnt[g], 1.f);
    hg[j] = gsum[g * DD + j] / cnt;
    hg[DD + j] = gmax[g * DD + j];
    __syncthreads();
    float a = pb[j];
    for (int k = 0; k < 2 * DD; ++k) a += hg[k] * pW[(size_t)k * DD + j];
    p1[j] = siluf(a);
    __syncthreads();
    a = hb1[j];
    for (int k = 0; k < DD; ++k) a += p1[k] * hW1[(size_t)k * DD + j];
    p2[j] = siluf(a);
    __syncthreads();
    if (j < DD / 2) {
        a = hb2[j];
        for (int k = 0; k < DD; ++k) a += p2[k] * hW2[(size_t)k * (DD / 2) + j];
        p3[j] = siluf(a);
    }
    __syncthreads();
    float v = (j < DD / 2) ? p3[j] * hW3[j] : 0.f;
#pragma unroll
    for (int off = 32; off > 0; off >>= 1) v += __shfl_down(v, off, 64);
    if ((j & 63) == 0) red[j >> 6] = v;
    __syncthreads();
    if (j == 0) {
        float s = 0.f;
        for (int w = 0; w < 6; ++w) s += red[w];
        out[g] = s + hb3[0];
    }
}

static inline int gemm_grid(int M, int N) {
    const int nr = (M + 127) >> 7, nc = N >> 7;
    return ((nr + 7) >> 3) * nc * 8;
}

extern "C" void kernel_launch(void* const* d_in, const int* in_sizes, int n_in,
                              void* d_out, int out_size, void* d_ws, size_t ws_size,
                              hipStream_t stream) {
    (void)in_sizes; (void)n_in; (void)out_size; (void)ws_size;
    const float* x      = (const float*)d_in[0];
    const float* pos    = (const float*)d_in[1];
    const int*   ei     = (const int*)d_in[2];
    const int*   batch  = (const int*)d_in[3];
    const float* emb_W  = (const float*)d_in[4];
    const float* emb_b  = (const float*)d_in[5];
    const float* emb_g  = (const float*)d_in[6];
    const float* emb_be = (const float*)d_in[7];
    const float* eW1    = (const float*)d_in[8];
    const float* eb1    = (const float*)d_in[9];
    const float* eW2    = (const float*)d_in[10];
    const float* eb2    = (const float*)d_in[11];
    const float* e_g    = (const float*)d_in[12];
    const float* e_be   = (const float*)d_in[13];
    const float* Wl     = (const float*)d_in[14];
    const float* bl     = (const float*)d_in[15];
    const float* Wr     = (const float*)d_in[16];
    const float* br     = (const float*)d_in[17];
    const float* We     = (const float*)d_in[18];
    const float* att    = (const float*)d_in[19];
    const float* cb     = (const float*)d_in[20];
    const float* bn_g   = (const float*)d_in[21];
    const float* bn_b   = (const float*)d_in[22];
    const float* bn_m   = (const float*)d_in[23];
    const float* bn_v   = (const float*)d_in[24];
    const float* pW     = (const float*)d_in[25];
    const float* pb     = (const float*)d_in[26];
    const float* hW1    = (const float*)d_in[27];
    const float* hb1    = (const float*)d_in[28];
    const float* hW2    = (const float*)d_in[29];
    const float* hb2    = (const float*)d_in[30];
    const float* hW3    = (const float*)d_in[31];
    const float* hb3    = (const float*)d_in[32];

    char* wp = (char*)d_ws;
    auto carve = [&](size_t bytes) -> void* {
        void* p = (void*)wp;
        wp += (bytes + 255) & ~(size_t)255;
        return p;
    };
    float* h      = (float*)carve((size_t)NN * DD * 4);
    __hip_bfloat16* hbf = (__hip_bfloat16*)carve((size_t)NN * DD * 2);
    __hip_bfloat16* xlr = (__hip_bfloat16*)carve((size_t)NN * 768 * 2);
    __hip_bfloat16* ebf = (__hip_bfloat16*)carve((size_t)EE * DD * 2);
    float* logits = (float*)carve((size_t)EE * HH * 4);
    int* deg      = (int*)carve((size_t)NN * 4);
    int* cursor   = (int*)carve((size_t)NN * 4);
    int* rp       = (int*)carve((size_t)(NN + 1) * 4);
    int* col_e    = (int*)carve((size_t)EE * 4);
    int* src_p    = (int*)carve((size_t)EE * 4);
    int* dst_p    = (int*)carve((size_t)EE * 4);
    float* gsum   = (float*)carve((size_t)GG * DD * 4);
    float* gmax   = (float*)carve((size_t)GG * DD * 4);
    float* gcnt   = (float*)carve((size_t)GG * 4);
    __hip_bfloat16* Wlrt = (__hip_bfloat16*)carve((size_t)LL * 768 * DD * 2);
    __hip_bfloat16* Wet  = (__hip_bfloat16*)carve((size_t)LL * DD * DD * 2);
    float* blr    = (float*)carve((size_t)LL * 768 * 4);
    __hip_bfloat16* eW1t = (__hip_bfloat16*)carve((size_t)DD * 128 * 2);
    __hip_bfloat16* eW2t = (__hip_bfloat16*)carve((size_t)DD * DD * 2);

    // encoder t-chunk aliases xlr (dead during encoder): CHUNK*384*2 = 30.72MB = |xlr|
    __hip_bfloat16* tc = xlr;

    hipMemsetAsync(deg, 0, (size_t)NN * 4, stream);
    hipMemsetAsync(cursor, 0, (size_t)NN * 4, stream);

    // ---- weight prep ----
    {
        const int nblkLR = (int)(((size_t)LL * 768 * DD + 255) / 256);
        const int nblk6 = (int)(((size_t)LL * DD * DD + 255) / 256);
        k_twlr<<<nblkLR, 256, 0, stream>>>(Wl, Wr, Wlrt);
        k_tw<<<nblk6, 256, 0, stream>>>(We, Wet, LL);
        k_blr<<<(LL * 768 + 255) / 256, 256, 0, stream>>>(bl, br, blr);
        k_tw<<<(DD * DD + 255) / 256, 256, 0, stream>>>(eW2, eW2t, 1);
        k_tw1<<<(DD * 128 + 255) / 256, 256, 0, stream>>>(eW1, eW1t);
    }

    // ---- node embedding ----
    k_node_embed<<<NN, 384, 0, stream>>>(x, emb_W, emb_b, emb_g, emb_be, h, hbf);

    // ---- CSR + edge permutation ----
    k_deg<<<(EE + 255) / 256, 256, 0, stream>>>(ei, deg);
    k_scan<<<1, 1024, 0, stream>>>(deg, rp);
    k_scatter<<<(EE + 255) / 256, 256, 0, stream>>>(ei, rp, cursor, col_e);
    k_perm<<<(EE + 255) / 256, 256, 0, stream>>>(ei, col_e, src_p, dst_p);

    // ---- edge encoder (5 chunks, CSR order): rbf-in-GEMM1 -> tc -> GEMM2 -> ebf; LN in-place
    for (int c0 = 0; c0 < EE; c0 += CHUNK) {
        const int cm = (EE - c0 < CHUNK) ? (EE - c0) : CHUNK;
        k_gemm_rbf<<<gemm_grid(cm, DD), 256, 0, stream>>>(pos, src_p, dst_p, c0, cm,
                                                          eW1t, eb1, tc);
        k_gemm_bt<true, false><<<gemm_grid(cm, DD), 256, 0, stream>>>(tc, eW2t, eb2,
                                                                      ebf + (size_t)c0 * DD, cm, DD, DD);
    }
    k_ln_rows<<<EE / 8, 512, 0, stream>>>(ebf, e_g, e_be);

    // ---- layers ----
    for (int i = 0; i < LL; ++i) {
        const __hip_bfloat16* Wlrt_i = Wlrt + (size_t)i * 768 * DD;
        const __hip_bfloat16* Wet_i  = Wet + (size_t)i * DD * DD;
        const float* blr_i = blr + (size_t)i * 768;
        const float* att_i = att + (size_t)i * HH * CC;
        const float* cb_i  = cb + (size_t)i * DD;
        const float* bng_i = bn_g + (size_t)i * DD;
        const float* bnb_i = bn_b + (size_t)i * DD;
        const float* bnm_i = bn_m + (size_t)i * DD;
        const float* bnv_i = bn_v + (size_t)i * DD;

        k_gemm_bt<true, false><<<gemm_grid(NN, 768), 256, 0, stream>>>(hbf, Wlrt_i, blr_i, xlr,
                                                                       NN, 768, DD);
        k_gemm_attn<<<gemm_grid(EE, DD), 256, 0, stream>>>(ebf, Wet_i, xlr, src_p, dst_p,
                                                           att_i, logits, EE, DD);
        k_node_aggr<<<(NN + 3) / 4, 256, 0, stream>>>(logits, xlr, src_p, rp, cb_i, bng_i, bnb_i,
                                                      bnm_i, bnv_i, h, hbf);
    }

    // ---- pooling + head ----
    hipMemsetAsync(gsum, 0, (size_t)GG * DD * 4, stream);
    hipMemsetAsync(gcnt, 0, (size_t)GG * 4, stream);
    k_fill<<<(GG * DD + 255) / 256, 256, 0, stream>>>(gmax, -INFINITY, GG * DD);
    k_pool2<<<(NN + 255) / 256, 384, 0, stream>>>(h, batch, gsum, gmax, gcnt);
    k_head<<<GG, 384, 0, stream>>>(gsum, gmax, gcnt, pW, pb, hW1, hb1, hW2, hb2, hW3, hb3,
                                   (float*)d_out);
}

// Round 13
// 1569.641 us; speedup vs baseline: 1.2084x; 1.1309x over previous
//
#include <hip/hip_runtime.h>
#include <hip/hip_bf16.h>
#include <math.h>

#define NN 20000
#define EE 200000
#define GG 32
#define DD 384
#define HH 12
#define CC 32
#define LL 6
#define NRBF 100
#define CHUNK 40000

typedef short s16x8 __attribute__((ext_vector_type(8)));
typedef float f32x4 __attribute__((ext_vector_type(4)));
typedef unsigned int u32;

__device__ __forceinline__ float siluf(float x) { return x / (1.f + __expf(-x)); }
__device__ __forceinline__ float bf2f(unsigned short u) {
    return __uint_as_float(((unsigned int)u) << 16);
}

__device__ __forceinline__ void atomicMaxF(float* addr, float val) {
    if (val >= 0.f) atomicMax((int*)addr, __float_as_int(val));
    else atomicMin((unsigned int*)addr, __float_as_uint(val));
}

// async global->LDS, 16B per lane; LDS dest = wave-uniform base + lane*16
__device__ __forceinline__ void gload16(const void* g, void* l) {
    __builtin_amdgcn_global_load_lds((const __attribute__((address_space(1))) u32*)g,
                                     (__attribute__((address_space(3))) u32*)l, 16, 0, 0);
}

// XCD-aware tile decode: col-tiles of one row-tile run consecutively on ONE XCD
// (dispatch round-robins XCDs by linear workgroup id) -> A row-tile stays L2-hot,
// A read from HBM exactly once (verified round 7: FETCH 301->156 MB).
__device__ __forceinline__ bool tile_decode(int NC, int nrows, int& rowt, int& col) {
    const int t = blockIdx.x;
    const int q = t >> 3;
    col = q % NC;
    rowt = (q / NC) * 8 + (t & 7);
    return rowt < nrows;
}

// Symbol the harness template named; defined for safety, never launched.
__global__ void EquivariantProteinGNN_45552423141948_kernel() {}

// ---- shared BK=32 K-loop (128x128 tile, 4 waves, 16KB As + 16KB Bs).
// BK=64 tried in round 9: occupancy 31%->21%, net regression -> reverted (m132 analog).
// LDS row = 64B = 4 chunks of 16B, chunk-swizzled c ^= (row>>1)&3 via pre-swizzled
// global SOURCE + swizzled READ (same involution both sides; linear gload_lds dest).
__device__ __forceinline__ void gemm_kloop(const __hip_bfloat16* __restrict__ A,
                                           const __hip_bfloat16* __restrict__ Bt,
                                           int M, int K, int m0, int n0,
                                           unsigned short* As, unsigned short* Bs,
                                           f32x4 (&acc)[4][4]) {
    char* AsB = (char*)As;
    char* BsB = (char*)Bs;
    const int t = threadIdx.x;
    const int w = t >> 6, l = t & 63;
    const int wr = w >> 1, wc = w & 1;

    const int seg0 = 2 * w, seg1 = seg0 + 1;
    const int r0s = seg0 * 16 + (l >> 2);
    const int r1s = seg1 * 16 + (l >> 2);
    const int cg0 = (l & 3) ^ ((r0s >> 1) & 3);
    const int cg1 = (l & 3) ^ ((r1s >> 1) & 3);
    const size_t aSrc0 = (size_t)min(m0 + r0s, M - 1) * K + cg0 * 8;
    const size_t aSrc1 = (size_t)min(m0 + r1s, M - 1) * K + cg1 * 8;
    const size_t bSrc0 = (size_t)(n0 + r0s) * K + cg0 * 8;
    const size_t bSrc1 = (size_t)(n0 + r1s) * K + cg1 * 8;
    unsigned short* AsW0 = As + seg0 * 512;
    unsigned short* AsW1 = As + seg1 * 512;
    unsigned short* BsW0 = Bs + seg0 * 512;
    unsigned short* BsW1 = Bs + seg1 * 512;

    int aoff[4], boff[4];
#pragma unroll
    for (int m = 0; m < 4; ++m) {
        const int row = wr * 64 + m * 16 + (l & 15);
        aoff[m] = row * 64 + ((((l >> 4)) ^ ((row >> 1) & 3)) << 4);
        const int rowb = wc * 64 + m * 16 + (l & 15);
        boff[m] = rowb * 64 + ((((l >> 4)) ^ ((rowb >> 1) & 3)) << 4);
    }

    for (int kk = 0; kk < K; kk += 32) {
        __syncthreads();
        gload16(A + aSrc0 + kk, AsW0);
        gload16(A + aSrc1 + kk, AsW1);
        gload16(Bt + bSrc0 + kk, BsW0);
        gload16(Bt + bSrc1 + kk, BsW1);
        __syncthreads();
        s16x8 af[4], bfr[4];
#pragma unroll
        for (int m = 0; m < 4; ++m) af[m] = *(const s16x8*)(AsB + aoff[m]);
#pragma unroll
        for (int n = 0; n < 4; ++n) bfr[n] = *(const s16x8*)(BsB + boff[n]);
#pragma unroll
        for (int m = 0; m < 4; ++m)
#pragma unroll
            for (int n = 0; n < 4; ++n)
                acc[m][n] = __builtin_amdgcn_mfma_f32_16x16x32_bf16(af[m], bfr[n], acc[m][n], 0, 0, 0);
    }
}

// ============ bf16 MFMA GEMM: C[M][N] = A[M][K] @ Bt[N][K]^T (+bias)(+silu) -> bf16 ============
// launch_bounds(256,4): cap unified VGPR+AGPR at 128/wave -> 4 waves/SIMD (was 144 -> 3).
template<bool BIAS, bool SILU>
__global__ __launch_bounds__(256, 4) void k_gemm_bt(const __hip_bfloat16* __restrict__ A,
                                                    const __hip_bfloat16* __restrict__ Bt,
                                                    const float* __restrict__ bias,
                                                    __hip_bfloat16* __restrict__ Cmat,
                                                    int M, int N, int K) {
    int rowt, colt;
    if (!tile_decode(N >> 7, (M + 127) >> 7, rowt, colt)) return;
    const int m0 = rowt << 7, n0 = colt << 7;

    __shared__ unsigned short As[128 * 32];
    __shared__ unsigned short Bs[128 * 32];
    const int l = threadIdx.x & 63;
    const int w = threadIdx.x >> 6;
    const int wr = w >> 1, wc = w & 1;

    f32x4 acc[4][4] = {};
    gemm_kloop(A, Bt, M, K, m0, n0, As, Bs, acc);

#pragma unroll
    for (int n = 0; n < 4; ++n) {
        const int col = n0 + wc * 64 + n * 16 + (l & 15);
        const float bv = BIAS ? bias[col] : 0.f;
#pragma unroll
        for (int m = 0; m < 4; ++m) {
            const int rbase = m0 + wr * 64 + m * 16 + ((l >> 4) << 2);
#pragma unroll
            for (int r = 0; r < 4; ++r) {
                const int row = rbase + r;
                if (row < M) {
                    float v = acc[m][n][r] + bv;
                    if (SILU) v = siluf(v);
                    Cmat[(size_t)row * N + col] = __float2bfloat16(v);
                }
            }
        }
    }
}

// ===== encoder GEMM1 with A = RBF features computed in-register (no rbf kernel/buffer) =====
// A-tile staged via ds_write_b128, lane-linear: conflict-free; slot<->chunk involution kept.
__global__ __launch_bounds__(256, 4) void k_gemm_rbf(const float* __restrict__ pos,
                                                     const int* __restrict__ src_p,
                                                     const int* __restrict__ dst_p,
                                                     int e0, int cm,
                                                     const __hip_bfloat16* __restrict__ Bt,
                                                     const float* __restrict__ bias,
                                                     __hip_bfloat16* __restrict__ Cmat) {
    int rowt, colt;
    if (!tile_decode(DD >> 7, (cm + 127) >> 7, rowt, colt)) return;
    const int m0 = rowt << 7, n0 = colt << 7;

    __shared__ unsigned short As[128 * 32];
    __shared__ unsigned short Bs[128 * 32];
    char* AsB = (char*)As;
    char* BsB = (char*)Bs;
    const int t = threadIdx.x;
    const int w = t >> 6, l = t & 63;
    const int wr = w >> 1, wc = w & 1;

    const float spacing = 30.f / 99.f;
    const float gamma = 1.f / (spacing * spacing + 1e-8f);

    const int rA0 = t >> 2, rA1 = 64 + (t >> 2);
    const int sc = t & 3;
    const int cgA0 = sc ^ ((rA0 >> 1) & 3);
    const int cgA1 = sc ^ ((rA1 >> 1) & 3);
    float distA[2];
#pragma unroll
    for (int i = 0; i < 2; ++i) {
        const int row = i ? rA1 : rA0;
        const int e = e0 + min(m0 + row, cm - 1);
        const int sN = src_p[e], dN = dst_p[e];
        const float dx = pos[sN * 3 + 0] - pos[dN * 3 + 0];
        const float dy = pos[sN * 3 + 1] - pos[dN * 3 + 1];
        const float dz = pos[sN * 3 + 2] - pos[dN * 3 + 2];
        distA[i] = sqrtf(dx * dx + dy * dy + dz * dz);
    }

    const int seg0 = 2 * w, seg1 = seg0 + 1;
    const int r0s = seg0 * 16 + (l >> 2);
    const int r1s = seg1 * 16 + (l >> 2);
    const int cgB0 = (l & 3) ^ ((r0s >> 1) & 3);
    const int cgB1 = (l & 3) ^ ((r1s >> 1) & 3);
    const size_t bSrc0 = (size_t)(n0 + r0s) * 128 + cgB0 * 8;
    const size_t bSrc1 = (size_t)(n0 + r1s) * 128 + cgB1 * 8;
    unsigned short* BsW0 = Bs + seg0 * 512;
    unsigned short* BsW1 = Bs + seg1 * 512;

    int aoff[4], boff[4];
#pragma unroll
    for (int m = 0; m < 4; ++m) {
        const int row = wr * 64 + m * 16 + (l & 15);
        aoff[m] = row * 64 + ((((l >> 4)) ^ ((row >> 1) & 3)) << 4);
        const int rowb = wc * 64 + m * 16 + (l & 15);
        boff[m] = rowb * 64 + ((((l >> 4)) ^ ((rowb >> 1) & 3)) << 4);
    }

    f32x4 acc[4][4] = {};

    for (int kk = 0; kk < 128; kk += 32) {
        __syncthreads();
        gload16(Bt + bSrc0 + kk, BsW0);
        gload16(Bt + bSrc1 + kk, BsW1);
        uint4 pk[2];
#pragma unroll
        for (int i = 0; i < 2; ++i) {
            const int kb = kk + (i ? cgA1 : cgA0) * 8;
            const float dist = distA[i];
            u32 w4[4];
#pragma unroll
            for (int j = 0; j < 4; ++j) {
                const int k0 = kb + 2 * j, k1 = k0 + 1;
                const float d0 = dist - (float)k0 * spacing;
                const float d1 = dist - (float)k1 * spacing;
                const float f0 = (k0 < NRBF) ? __expf(-gamma * d0 * d0) : 0.f;
                const float f1 = (k1 < NRBF) ? __expf(-gamma * d1 * d1) : 0.f;
                w4[j] = (u32)__bfloat16_as_ushort(__float2bfloat16(f0)) |
                        ((u32)__bfloat16_as_ushort(__float2bfloat16(f1)) << 16);
            }
            pk[i] = make_uint4(w4[0], w4[1], w4[2], w4[3]);
        }
        *(uint4*)(AsB + t * 16) = pk[0];
        *(uint4*)(AsB + 4096 + t * 16) = pk[1];
        __syncthreads();
        s16x8 af[4], bfr[4];
#pragma unroll
        for (int m = 0; m < 4; ++m) af[m] = *(const s16x8*)(AsB + aoff[m]);
#pragma unroll
        for (int n = 0; n < 4; ++n) bfr[n] = *(const s16x8*)(BsB + boff[n]);
#pragma unroll
        for (int m = 0; m < 4; ++m)
#pragma unroll
            for (int n = 0; n < 4; ++n)
                acc[m][n] = __builtin_amdgcn_mfma_f32_16x16x32_bf16(af[m], bfr[n], acc[m][n], 0, 0, 0);
    }

#pragma unroll
    for (int n = 0; n < 4; ++n) {
        const int col = n0 + wc * 64 + n * 16 + (l & 15);
        const float bv = bias[col];
#pragma unroll
        for (int m = 0; m < 4; ++m) {
            const int rbase = m0 + wr * 64 + m * 16 + ((l >> 4) << 2);
#pragma unroll
            for (int r = 0; r < 4; ++r) {
                const int row = rbase + r;
                if (row < cm) {
                    Cmat[(size_t)row * DD + col] = __float2bfloat16(siluf(acc[m][n][r] + bv));
                }
            }
        }
    }
}

// ===== fused: ee = ebf @ Wet^T, then logits[p][h] over CSR-ordered edges =====
// Epilogue via per-wave LDS transpose (col^(row<<2), 0 conflicts in round-9/10 counters).
__global__ __launch_bounds__(256, 4) void k_gemm_attn(const __hip_bfloat16* __restrict__ A,
                                                      const __hip_bfloat16* __restrict__ Bt,
                                                      const __hip_bfloat16* __restrict__ xlr,
                                                      const int* __restrict__ src_p,
                                                      const int* __restrict__ dst_p,
                                                      const float* __restrict__ att_i,
                                                      float* __restrict__ logits,
                                                      int M, int K) {
    int rowt, colt;
    if (!tile_decode(DD >> 7, (M + 127) >> 7, rowt, colt)) return;
    const int m0 = rowt << 7, n0 = colt << 7;

    __shared__ char smem[16384];
    unsigned short* As = (unsigned short*)smem;
    unsigned short* Bs = (unsigned short*)(smem + 8192);
    const int l = threadIdx.x & 63;
    const int w = threadIdx.x >> 6;
    const int wr = w >> 1, wc = w & 1;

    f32x4 acc[4][4] = {};
    gemm_kloop(A, Bt, M, K, m0, n0, As, Bs, acc);

    __syncthreads();  // all waves done with As/Bs; reuse as per-wave epilogue scratch

    // ---- LDS-transpose epilogue ----
    float* ep = (float*)(smem + w * 4096);  // per-wave 16x64 f32
    const int row_l = l >> 2;               // 0..15: local edge row this lane reduces
    const int c0 = (l & 3) << 4;            // 16-col slice within the 64-col window
    const int gcol = n0 + wc * 64 + c0;
    const int hbase = (n0 + wc * 64) >> 5;  // first of 2 heads in this wave's window
    const int rswz = row_l << 2;

    float attv[16];
#pragma unroll
    for (int k = 0; k < 4; ++k)
        *(float4*)(attv + 4 * k) = *(const float4*)(att_i + gcol + 4 * k);

#pragma unroll
    for (int m = 0; m < 4; ++m) {
        // issue independent gathers FIRST (latency hides under the LDS transpose)
        const int growu = m0 + wr * 64 + m * 16 + row_l;
        const int grow = min(growu, M - 1);
        const int s = src_p[grow], d = dst_p[grow];
        const uint4 vl0 = *(const uint4*)(xlr + (size_t)s * 768 + gcol);
        const uint4 vl1 = *(const uint4*)(xlr + (size_t)s * 768 + gcol + 8);
        const uint4 vr0 = *(const uint4*)(xlr + (size_t)d * 768 + 384 + gcol);
        const uint4 vr1 = *(const uint4*)(xlr + (size_t)d * 768 + 384 + gcol + 8);

        // scatter this wave's 16x64 acc window into LDS (col ^ row<<2: conflict-free)
#pragma unroll
        for (int n = 0; n < 4; ++n)
#pragma unroll
            for (int r = 0; r < 4; ++r) {
                const int row = ((l >> 4) << 2) + r;
                const int col = (n << 4) + (l & 15);
                ep[(row << 6) + (col ^ (row << 2))] = acc[m][n][r];
            }
        // transposed read: lane owns one row, 16 contiguous cols (4x f32x4)
        float av[16];
#pragma unroll
        for (int k = 0; k < 4; ++k) {
            const int sc0 = (c0 + (k << 2)) ^ rswz;
            *(f32x4*)(av + 4 * k) = *(const f32x4*)(ep + (row_l << 6) + sc0);
        }
        const u32 lw[8] = {vl0.x, vl0.y, vl0.z, vl0.w, vl1.x, vl1.y, vl1.z, vl1.w};
        const u32 rw[8] = {vr0.x, vr0.y, vr0.z, vr0.w, vr1.x, vr1.y, vr1.z, vr1.w};
        float part = 0.f;
#pragma unroll
        for (int q = 0; q < 8; ++q) {
            float v0 = av[2 * q] + bf2f((unsigned short)(lw[q] & 0xffff)) +
                       bf2f((unsigned short)(rw[q] & 0xffff));
            float v1 = av[2 * q + 1] + bf2f((unsigned short)(lw[q] >> 16)) +
                       bf2f((unsigned short)(rw[q] >> 16));
            v0 = (v0 > 0.f) ? v0 : 0.2f * v0;
            v1 = (v1 > 0.f) ? v1 : 0.2f * v1;
            part += v0 * attv[2 * q] + v1 * attv[2 * q + 1];
        }
        part += __shfl_xor(part, 1, 64);  // combine the 2 half-head lanes
        if (growu < M && (l & 1) == 0)
            logits[(size_t)growu * HH + hbase + ((l & 2) >> 1)] = part;
    }
}

// ============ weight prep ============
__global__ void k_tw(const float* __restrict__ in, __hip_bfloat16* __restrict__ out, int nmat) {
    const size_t idx = (size_t)blockIdx.x * 256 + threadIdx.x;
    if (idx >= (size_t)nmat * DD * DD) return;
    const int m = idx / (DD * DD);
    const int rem = idx - (size_t)m * DD * DD;
    const int n = rem / DD, k = rem - n * DD;
    out[idx] = __float2bfloat16(in[(size_t)m * DD * DD + (size_t)k * DD + n]);
}

// fused Wl|Wr -> bf16 [L][768(n)][384(k)] transposed
__global__ void k_twlr(const float* __restrict__ Wl, const float* __restrict__ Wr,
                       __hip_bfloat16* __restrict__ out) {
    const size_t idx = (size_t)blockIdx.x * 256 + threadIdx.x;
    if (idx >= (size_t)LL * 768 * DD) return;
    const int i = idx / (768 * DD);
    const int rem = idx - (size_t)i * 768 * DD;
    const int n = rem / DD, k = rem - n * DD;
    const float v = (n < DD) ? Wl[(size_t)i * DD * DD + (size_t)k * DD + n]
                             : Wr[(size_t)i * DD * DD + (size_t)k * DD + (n - DD)];
    out[idx] = __float2bfloat16(v);
}

__global__ void k_blr(const float* __restrict__ bl, const float* __restrict__ br,
                      float* __restrict__ blr) {
    const int idx = blockIdx.x * 256 + threadIdx.x;
    if (idx >= LL * 768) return;
    const int i = idx / 768, c = idx - i * 768;
    blr[idx] = (c < DD) ? bl[i * DD + c] : br[i * DD + c - DD];
}

// eW1 f32 [100][384] -> bf16 [384][128] transposed, k>=100 zero-padded
__global__ void k_tw1(const float* __restrict__ in, __hip_bfloat16* __restrict__ out) {
    const int idx = blockIdx.x * 256 + threadIdx.x;
    if (idx >= DD * 128) return;
    const int n = idx >> 7, k = idx & 127;
    out[idx] = __float2bfloat16(k < NRBF ? in[(size_t)k * DD + n] : 0.f);
}

// ============ in-place row LayerNorm on bf16 [rows][384]; one wave per row ============
__global__ __launch_bounds__(512) void k_ln_rows(__hip_bfloat16* __restrict__ u,
                                                 const float* __restrict__ g,
                                                 const float* __restrict__ be) {
    const int w = threadIdx.x >> 6, l = threadIdx.x & 63;
    const int row = blockIdx.x * 8 + w;
    float vals[8];
    float s = 0.f, q = 0.f;
    if (l < 48) {
        const uint4 vu = *(const uint4*)(u + (size_t)row * DD + 8 * l);
        const unsigned int* uw = (const unsigned int*)&vu;
#pragma unroll
        for (int i = 0; i < 4; ++i) {
            vals[2 * i] = bf2f((unsigned short)(uw[i] & 0xffff));
            vals[2 * i + 1] = bf2f((unsigned short)(uw[i] >> 16));
        }
#pragma unroll
        for (int i = 0; i < 8; ++i) { s += vals[i]; q += vals[i] * vals[i]; }
    }
#pragma unroll
    for (int off = 1; off < 64; off <<= 1) {
        s += __shfl_xor(s, off, 64);
        q += __shfl_xor(q, off, 64);
    }
    const float mu = s / DD;
    const float rs = rsqrtf(q / DD - mu * mu + 1e-5f);
    if (l < 48) {
        unsigned int ow[4];
        const float4 g0 = *(const float4*)(g + 8 * l);
        const float4 g1 = *(const float4*)(g + 8 * l + 4);
        const float4 b0 = *(const float4*)(be + 8 * l);
        const float4 b1 = *(const float4*)(be + 8 * l + 4);
        const float gv[8] = {g0.x, g0.y, g0.z, g0.w, g1.x, g1.y, g1.z, g1.w};
        const float bv[8] = {b0.x, b0.y, b0.z, b0.w, b1.x, b1.y, b1.z, b1.w};
#pragma unroll
        for (int i = 0; i < 4; ++i) {
            const float y0 = (vals[2 * i] - mu) * rs * gv[2 * i] + bv[2 * i];
            const float y1 = (vals[2 * i + 1] - mu) * rs * gv[2 * i + 1] + bv[2 * i + 1];
            const unsigned short h0 = __bfloat16_as_ushort(__float2bfloat16(y0));
            const unsigned short h1 = __bfloat16_as_ushort(__float2bfloat16(y1));
            ow[i] = (unsigned int)h0 | ((unsigned int)h1 << 16);
        }
        *(uint4*)(u + (size_t)row * DD + 8 * l) = *(uint4*)ow;
    }
}

// ============ node embedding ============
__global__ __launch_bounds__(384) void k_node_embed(const float* __restrict__ x,
                                                    const float* __restrict__ W,
                                                    const float* __restrict__ b,
                                                    const float* __restrict__ g,
                                                    const float* __restrict__ be,
                                                    float* __restrict__ h,
                                                    __hip_bfloat16* __restrict__ hb) {
    const int n = blockIdx.x, j = threadIdx.x;
    __shared__ float xrow[20];
    __shared__ float red[12];
    if (j < 20) xrow[j] = x[n * 20 + j];
    __syncthreads();
    float acc = b[j];
#pragma unroll
    for (int k = 0; k < 20; ++k) acc += xrow[k] * W[k * DD + j];
    float s = acc, q = acc * acc;
#pragma unroll
    for (int off = 32; off > 0; off >>= 1) {
        s += __shfl_down(s, off, 64);
        q += __shfl_down(q, off, 64);
    }
    const int wid = j >> 6;
    if ((j & 63) == 0) { red[wid] = s; red[6 + wid] = q; }
    __syncthreads();
    if (j == 0) {
        float ts = 0.f, tq = 0.f;
        for (int w = 0; w < 6; ++w) { ts += red[w]; tq += red[6 + w]; }
        float mu = ts / DD;
        red[0] = mu; red[6] = tq / DD - mu * mu;
    }
    __syncthreads();
    const float mu = red[0], var = red[6];
    float y = (acc - mu) * rsqrtf(var + 1e-5f) * g[j] + be[j];
    y = siluf(y);
    h[(size_t)n * DD + j] = y;
    hb[(size_t)n * DD + j] = __float2bfloat16(y);
}

// ============ CSR build over dst ============
__global__ void k_deg(const int* __restrict__ ei, int* __restrict__ deg) {
    int e = blockIdx.x * blockDim.x + threadIdx.x;
    if (e < EE) atomicAdd(&deg[ei[EE + e]], 1);
}

__global__ __launch_bounds__(1024) void k_scan(const int* __restrict__ deg, int* __restrict__ rp) {
    __shared__ int buf[1024];
    __shared__ int carry_s;
    const int tid = threadIdx.x;
    if (tid == 0) carry_s = 0;
    __syncthreads();
    for (int base = 0; base < NN; base += 1024) {
        int v = (base + tid < NN) ? deg[base + tid] : 0;
        buf[tid] = v;
        __syncthreads();
        for (int off = 1; off < 1024; off <<= 1) {
            int t = (tid >= off) ? buf[tid - off] : 0;
            __syncthreads();
            buf[tid] += t;
            __syncthreads();
        }
        const int incl = buf[tid];
        const int carry = carry_s;
        if (base + tid < NN) rp[base + tid] = carry + incl - v;
        __syncthreads();
        if (tid == 1023) carry_s = carry + incl;
        __syncthreads();
    }
    if (tid == 0) rp[NN] = carry_s;
}

__global__ void k_scatter(const int* __restrict__ ei, const int* __restrict__ rp,
                          int* __restrict__ cursor, int* __restrict__ col_e) {
    int e = blockIdx.x * blockDim.x + threadIdx.x;
    if (e < EE) {
        int d = ei[EE + e];
        int p = atomicAdd(&cursor[d], 1);
        col_e[rp[d] + p] = e;
    }
}

// p -> original edge col_e[p]; materialize permuted src/dst
__global__ void k_perm(const int* __restrict__ ei, const int* __restrict__ col_e,
                       int* __restrict__ src_p, int* __restrict__ dst_p) {
    int p = blockIdx.x * blockDim.x + threadIdx.x;
    if (p < EE) {
        const int e = col_e[p];
        src_p[p] = ei[e];
        dst_p[p] = ei[EE + e];
    }
}

// ============ per-node softmax + aggregate + BN + silu + residual ============
// Stats phase wave-parallelized: 4 lanes per head stride the edge list, then a
// 2-step shfl_xor reduce within each aligned 4-lane group (round-11, +55 us).
__global__ __launch_bounds__(256) void k_node_aggr(const float* __restrict__ logits,
                                                   const __hip_bfloat16* __restrict__ xlr,
                                                   const int* __restrict__ src_p,
                                                   const int* __restrict__ rp,
                                                   const float* __restrict__ cb_i,
                                                   const float* __restrict__ g_i,
                                                   const float* __restrict__ b_i,
                                                   const float* __restrict__ m_i,
                                                   const float* __restrict__ v_i,
                                                   float* __restrict__ h,
                                                   __hip_bfloat16* __restrict__ hb) {
    const int wv = threadIdx.x >> 6, l = threadIdx.x & 63;
    const int n = blockIdx.x * 4 + wv;
    if (n >= NN || l >= 48) return;
    const int beg = rp[n], end = rp[n + 1];
    const int head = l >> 2;
    const int j4 = l & 3;

    float mx = -INFINITY;
    for (int i = beg + j4; i < end; i += 4) mx = fmaxf(mx, logits[(size_t)i * HH + head]);
    mx = fmaxf(mx, __shfl_xor(mx, 1, 64));
    mx = fmaxf(mx, __shfl_xor(mx, 2, 64));
    float sum = 0.f;
    for (int i = beg + j4; i < end; i += 4) sum += __expf(logits[(size_t)i * HH + head] - mx);
    sum += __shfl_xor(sum, 1, 64);
    sum += __shfl_xor(sum, 2, 64);
    const float m_h = mx;
    const float inv_h = 1.f / (sum + 1e-16f);

    const int c0 = l * 8;
    float acc[8] = {};
    for (int i = beg; i < end; ++i) {
        const float a = __expf(logits[(size_t)i * HH + head] - m_h) * inv_h;
        const int s = src_p[i];
        const uint4 vx = *(const uint4*)(xlr + (size_t)s * 768 + c0);
        const u32* xw = (const u32*)&vx;
#pragma unroll
        for (int q = 0; q < 4; ++q) {
            acc[2 * q]     += bf2f((unsigned short)(xw[q] & 0xffff)) * a;
            acc[2 * q + 1] += bf2f((unsigned short)(xw[q] >> 16)) * a;
        }
    }
    const float4 cb0 = *(const float4*)(cb_i + c0), cb1 = *(const float4*)(cb_i + c0 + 4);
    const float4 gg0 = *(const float4*)(g_i + c0),  gg1 = *(const float4*)(g_i + c0 + 4);
    const float4 bb0 = *(const float4*)(b_i + c0),  bb1 = *(const float4*)(b_i + c0 + 4);
    const float4 mm0 = *(const float4*)(m_i + c0),  mm1 = *(const float4*)(m_i + c0 + 4);
    const float4 vv0 = *(const float4*)(v_i + c0),  vv1 = *(const float4*)(v_i + c0 + 4);
    const float cbv[8] = {cb0.x, cb0.y, cb0.z, cb0.w, cb1.x, cb1.y, cb1.z, cb1.w};
    const float gv[8]  = {gg0.x, gg0.y, gg0.z, gg0.w, gg1.x, gg1.y, gg1.z, gg1.w};
    const float bv[8]  = {bb0.x, bb0.y, bb0.z, bb0.w, bb1.x, bb1.y, bb1.z, bb1.w};
    const float mv[8]  = {mm0.x, mm0.y, mm0.z, mm0.w, mm1.x, mm1.y, mm1.z, mm1.w};
    const float vvv[8] = {vv0.x, vv0.y, vv0.z, vv0.w, vv1.x, vv1.y, vv1.z, vv1.w};
    float4 h0 = *(const float4*)(h + (size_t)n * DD + c0);
    float4 h1 = *(const float4*)(h + (size_t)n * DD + c0 + 4);
    float hv[8] = {h0.x, h0.y, h0.z, h0.w, h1.x, h1.y, h1.z, h1.w};
    unsigned int ow[4];
#pragma unroll
    for (int q = 0; q < 8; ++q) {
        float o = acc[q] + cbv[q];
        o = (o - mv[q]) * rsqrtf(vvv[q] + 1e-5f) * gv[q] + bv[q];
        hv[q] = siluf(o) + hv[q];
    }
#pragma unroll
    for (int q = 0; q < 4; ++q) {
        const unsigned short b0 = __bfloat16_as_ushort(__float2bfloat16(hv[2 * q]));
        const unsigned short b1 = __bfloat16_as_ushort(__float2bfloat16(hv[2 * q + 1]));
        ow[q] = (unsigned int)b0 | ((unsigned int)b1 << 16);
    }
    *(float4*)(h + (size_t)n * DD + c0) = make_float4(hv[0], hv[1], hv[2], hv[3]);
    *(float4*)(h + (size_t)n * DD + c0 + 4) = make_float4(hv[4], hv[5], hv[6], hv[7]);
    *(uint4*)(hb + (size_t)n * DD + c0) = *(uint4*)ow;
}

// ============ pooling: segmented (batch sorted) ============
__global__ void k_fill(float* __restrict__ p, float v, int n) {
    int i = blockIdx.x * blockDim.x + threadIdx.x;
    if (i < n) p[i] = v;
}

__global__ __launch_bounds__(384) void k_pool2(const float* __restrict__ h,
                                               const int* __restrict__ batch,
                                               float* __restrict__ gsum,
                                               float* __restrict__ gmax,
                                               float* __restrict__ gcnt) {
    const int j = threadIdx.x;
    const int n0 = blockIdx.x * 256;
    const int n1 = min(n0 + 256, NN);
    int cur = batch[n0];
    float s = 0.f, mx = -INFINITY;
    int cnt = 0;
    for (int n = n0; n < n1; ++n) {
        const int g = batch[n];
        if (g != cur) {
            atomicAdd(&gsum[cur * DD + j], s);
            atomicMaxF(&gmax[cur * DD + j], mx);
            if (j == 0) atomicAdd(&gcnt[cur], (float)cnt);
            s = 0.f; mx = -INFINITY; cnt = 0; cur = g;
        }
        const float v = h[(size_t)n * DD + j];
        s += v; mx = fmaxf(mx, v); ++cnt;
    }
    atomicAdd(&gsum[cur * DD + j], s);
    atomicMaxF(&gmax[cur * DD + j], mx);
    if (j == 0) atomicAdd(&gcnt[cur], (float)cnt);
}

// ============ per-graph MLP head (fp32 output) ============
__global__ __launch_bounds__(384) void k_head(const float* __restrict__ gsum,
                                              const float* __restrict__ gmax,
                                              const float* __restrict__ gcnt,
                                              const float* __restrict__ pW,
                                              const float* __restrict__ pb,
                                              const float* __restrict__ hW1,
                                              const float* __restrict__ hb1,
                                              const float* __restrict__ hW2,
                                              const float* __restrict__ hb2,
                                              const float* __restrict__ hW3,
                                              const float* __restrict__ hb3,
                                              float* __restrict__ out) {
    const int g = blockIdx.x, j = threadIdx.x;
    __shared__ float hg[2 * DD];
    __shared__ float p1[DD];
    __shared__ float p2[DD];
    __shared__ float p3[DD / 2];
    __shared__ float red[6];
    const float cnt = fmaxf(gcnt[g], 1.f);
    hg[j] = gsum[g * DD + j] / cnt;
    hg[DD + j] = gmax[g * DD + j];
    __syncthreads();
    float a = pb[j];
    for (int k = 0; k < 2 * DD; ++k) a += hg[k] * pW[(size_t)k * DD + j];
    p1[j] = siluf(a);
    __syncthreads();
    a = hb1[j];
    for (int k = 0; k < DD; ++k) a += p1[k] * hW1[(size_t)k * DD + j];
    p2[j] = siluf(a);
    __syncthreads();
    if (j < DD / 2) {
        a = hb2[j];
        for (int k = 0; k < DD; ++k) a += p2[k] * hW2[(size_t)k * (DD / 2) + j];
        p3[j] = siluf(a);
    }
    __syncthreads();
    float v = (j < DD / 2) ? p3[j] * hW3[j] : 0.f;
#pragma unroll
    for (int off = 32; off > 0; off >>= 1) v += __shfl_down(v, off, 64);
    if ((j & 63) == 0) red[j >> 6] = v;
    __syncthreads();
    if (j == 0) {
        float s = 0.f;
        for (int w = 0; w < 6; ++w) s += red[w];
        out[g] = s + hb3[0];
    }
}

static inline int gemm_grid(int M, int N) {
    const int nr = (M + 127) >> 7, nc = N >> 7;
    return ((nr + 7) >> 3) * nc * 8;
}

extern "C" void kernel_launch(void* const* d_in, const int* in_sizes, int n_in,
                              void* d_out, int out_size, void* d_ws, size_t ws_size,
                              hipStream_t stream) {
    (void)in_sizes; (void)n_in; (void)out_size; (void)ws_size;
    const float* x      = (const float*)d_in[0];
    const float* pos    = (const float*)d_in[1];
    const int*   ei     = (const int*)d_in[2];
    const int*   batch  = (const int*)d_in[3];
    const float* emb_W  = (const float*)d_in[4];
    const float* emb_b  = (const float*)d_in[5];
    const float* emb_g  = (const float*)d_in[6];
    const float* emb_be = (const float*)d_in[7];
    const float* eW1    = (const float*)d_in[8];
    const float* eb1    = (const float*)d_in[9];
    const float* eW2    = (const float*)d_in[10];
    const float* eb2    = (const float*)d_in[11];
    const float* e_g    = (const float*)d_in[12];
    const float* e_be   = (const float*)d_in[13];
    const float* Wl     = (const float*)d_in[14];
    const float* bl     = (const float*)d_in[15];
    const float* Wr     = (const float*)d_in[16];
    const float* br     = (const float*)d_in[17];
    const float* We     = (const float*)d_in[18];
    const float* att    = (const float*)d_in[19];
    const float* cb     = (const float*)d_in[20];
    const float* bn_g   = (const float*)d_in[21];
    const float* bn_b   = (const float*)d_in[22];
    const float* bn_m   = (const float*)d_in[23];
    const float* bn_v   = (const float*)d_in[24];
    const float* pW     = (const float*)d_in[25];
    const float* pb     = (const float*)d_in[26];
    const float* hW1    = (const float*)d_in[27];
    const float* hb1    = (const float*)d_in[28];
    const float* hW2    = (const float*)d_in[29];
    const float* hb2    = (const float*)d_in[30];
    const float* hW3    = (const float*)d_in[31];
    const float* hb3    = (const float*)d_in[32];

    char* wp = (char*)d_ws;
    auto carve = [&](size_t bytes) -> void* {
        void* p = (void*)wp;
        wp += (bytes + 255) & ~(size_t)255;
        return p;
    };
    float* h      = (float*)carve((size_t)NN * DD * 4);
    __hip_bfloat16* hbf = (__hip_bfloat16*)carve((size_t)NN * DD * 2);
    __hip_bfloat16* xlr = (__hip_bfloat16*)carve((size_t)NN * 768 * 2);
    __hip_bfloat16* ebf = (__hip_bfloat16*)carve((size_t)EE * DD * 2);
    float* logits = (float*)carve((size_t)EE * HH * 4);
    int* deg      = (int*)carve((size_t)NN * 4);
    int* cursor   = (int*)carve((size_t)NN * 4);
    int* rp       = (int*)carve((size_t)(NN + 1) * 4);
    int* col_e    = (int*)carve((size_t)EE * 4);
    int* src_p    = (int*)carve((size_t)EE * 4);
    int* dst_p    = (int*)carve((size_t)EE * 4);
    float* gsum   = (float*)carve((size_t)GG * DD * 4);
    float* gmax   = (float*)carve((size_t)GG * DD * 4);
    float* gcnt   = (float*)carve((size_t)GG * 4);
    __hip_bfloat16* Wlrt = (__hip_bfloat16*)carve((size_t)LL * 768 * DD * 2);
    __hip_bfloat16* Wet  = (__hip_bfloat16*)carve((size_t)LL * DD * DD * 2);
    float* blr    = (float*)carve((size_t)LL * 768 * 4);
    __hip_bfloat16* eW1t = (__hip_bfloat16*)carve((size_t)DD * 128 * 2);
    __hip_bfloat16* eW2t = (__hip_bfloat16*)carve((size_t)DD * DD * 2);

    // encoder t-chunk aliases xlr (dead during encoder): CHUNK*384*2 = 30.72MB = |xlr|
    __hip_bfloat16* tc = xlr;

    hipMemsetAsync(deg, 0, (size_t)NN * 4, stream);
    hipMemsetAsync(cursor, 0, (size_t)NN * 4, stream);

    // ---- weight prep ----
    {
        const int nblkLR = (int)(((size_t)LL * 768 * DD + 255) / 256);
        const int nblk6 = (int)(((size_t)LL * DD * DD + 255) / 256);
        k_twlr<<<nblkLR, 256, 0, stream>>>(Wl, Wr, Wlrt);
        k_tw<<<nblk6, 256, 0, stream>>>(We, Wet, LL);
        k_blr<<<(LL * 768 + 255) / 256, 256, 0, stream>>>(bl, br, blr);
        k_tw<<<(DD * DD + 255) / 256, 256, 0, stream>>>(eW2, eW2t, 1);
        k_tw1<<<(DD * 128 + 255) / 256, 256, 0, stream>>>(eW1, eW1t);
    }

    // ---- node embedding ----
    k_node_embed<<<NN, 384, 0, stream>>>(x, emb_W, emb_b, emb_g, emb_be, h, hbf);

    // ---- CSR + edge permutation ----
    k_deg<<<(EE + 255) / 256, 256, 0, stream>>>(ei, deg);
    k_scan<<<1, 1024, 0, stream>>>(deg, rp);
    k_scatter<<<(EE + 255) / 256, 256, 0, stream>>>(ei, rp, cursor, col_e);
    k_perm<<<(EE + 255) / 256, 256, 0, stream>>>(ei, col_e, src_p, dst_p);

    // ---- edge encoder (5 chunks, CSR order): rbf-in-GEMM1 -> tc -> GEMM2 -> ebf; LN in-place
    for (int c0 = 0; c0 < EE; c0 += CHUNK) {
        const int cm = (EE - c0 < CHUNK) ? (EE - c0) : CHUNK;
        k_gemm_rbf<<<gemm_grid(cm, DD), 256, 0, stream>>>(pos, src_p, dst_p, c0, cm,
                                                          eW1t, eb1, tc);
        k_gemm_bt<true, false><<<gemm_grid(cm, DD), 256, 0, stream>>>(tc, eW2t, eb2,
                                                                      ebf + (size_t)c0 * DD, cm, DD, DD);
    }
    k_ln_rows<<<EE / 8, 512, 0, stream>>>(ebf, e_g, e_be);

    // ---- layers ----
    for (int i = 0; i < LL; ++i) {
        const __hip_bfloat16* Wlrt_i = Wlrt + (size_t)i * 768 * DD;
        const __hip_bfloat16* Wet_i  = Wet + (size_t)i * DD * DD;
        const float* blr_i = blr + (size_t)i * 768;
        const float* att_i = att + (size_t)i * HH * CC;
        const float* cb_i  = cb + (size_t)i * DD;
        const float* bng_i = bn_g + (size_t)i * DD;
        const float* bnb_i = bn_b + (size_t)i * DD;
        const float* bnm_i = bn_m + (size_t)i * DD;
        const float* bnv_i = bn_v + (size_t)i * DD;

        k_gemm_bt<true, false><<<gemm_grid(NN, 768), 256, 0, stream>>>(hbf, Wlrt_i, blr_i, xlr,
                                                                       NN, 768, DD);
        k_gemm_attn<<<gemm_grid(EE, DD), 256, 0, stream>>>(ebf, Wet_i, xlr, src_p, dst_p,
                                                           att_i, logits, EE, DD);
        k_node_aggr<<<(NN + 3) / 4, 256, 0, stream>>>(logits, xlr, src_p, rp, cb_i, bng_i, bnb_i,
                                                      bnm_i, bnv_i, h, hbf);
    }

    // ---- pooling + head ----
    hipMemsetAsync(gsum, 0, (size_t)GG * DD * 4, stream);
    hipMemsetAsync(gcnt, 0, (size_t)GG * 4, stream);
    k_fill<<<(GG * DD + 255) / 256, 256, 0, stream>>>(gmax, -INFINITY, GG * DD);
    k_pool2<<<(NN + 255) / 256, 384, 0, stream>>>(h, batch, gsum, gmax, gcnt);
    k_head<<<GG, 384, 0, stream>>>(gsum, gmax, gcnt, pW, pb, hW1, hb1, hW2, hb2, hW3, hb3,
                                   (float*)d_out);
}